// Round 7
// baseline (428.653 us; speedup 1.0000x reference)
//
#include <hip/hip_runtime.h>
#include <math.h>

#define N_GRD 4
#define M_SAT 32
#define C_CH  32
#define HK    64
#define WK    64
#define HO    65
#define WO    65
#define SAMPLE_ELEMS (C_CH * HK * WK)

typedef _Float16 h8 __attribute__((ext_vector_type(8)));
typedef float    f4 __attribute__((ext_vector_type(4)));
typedef unsigned int u32;

// ---- ws layout (float units) ----
#define OFF_INV    0                  // inv[0..35]; ws+48: 16B cnt scratch
#define OFF_S      64                 // 32 * 4225
#define OFF_CANDV  135264
#define OFF_CANDI  135776
#define OFF_DOTS   136288             // 512
#define OFF_PART   136800             // 32 m * 4 n * 80 xsl * 80 y = 819200
#define OFF_G2F    956000             // G2_HALFS/2 floats
#define OFF_SH     1824352            // 524288 granules * 8 halfs = 2097152 floats
#define OFF_S2G    3921504            // 32 m * 4096 raw squared-norm sums
#define G2_HALFS   1736704            // 2cp * 8cq * 64i * 4n * 106js * 4c

#define G2V_BLOCKS 848                // G2_HALFS/8 granules / 256
#define SH_BLOCKS  2048               // 524288/256
#define S2P_BLOCKS 256                // 32 m x 8 slices of 512 px (exact s2)
#define ZERO_BLOCKS 801               // partial 800 + dots/cnt 1
#define PREP_BLOCKS (G2V_BLOCKS + SH_BLOCKS + S2P_BLOCKS + N_GRD + ZERO_BLOCKS)

// ---------------------------------------------------------------------------
// K1 (fused prep), by blockIdx range:
//  [0,848)         g2 Toeplitz build, vectorized (1 thread = 1 granule)
//  [848,2896)      sh build: fp16 sat in DMA-granule layout (16B stores)
//  [2896,3152)     s2g: per-pixel sum over 32 channels of sat^2, EXACT serial
//                  ascending-c order (bit-identical to old SAT phase 1),
//                  spread 32m x 8 slices -> no per-CU straggler.
//  [3152,3156)     grd inv-norms
//  [3156,3957)     zero partial (819200 f) + dots (512 f) + cnt (4 f)
// ---------------------------------------------------------------------------
__global__ __launch_bounds__(256) void prep_kernel(const float* __restrict__ grd,
                                                   const float* __restrict__ sat,
                                                   _Float16* __restrict__ g2,
                                                   _Float16* __restrict__ sh,
                                                   float* __restrict__ s2g,
                                                   float* __restrict__ inv,
                                                   float* __restrict__ partial,
                                                   float* __restrict__ dots,
                                                   float* __restrict__ cntf) {
    const int bx = blockIdx.x;
    const int tid = threadIdx.x;

    if (bx < G2V_BLOCKS) {
        int g = bx * 256 + tid;            // granule index < 217088
        int t0 = g * 2;
        int js0 = t0 % 106;
        int r = t0 / 106;
        int n  = r & 3;
        int i  = (r >> 2) & 63;
        int cq = (r >> 8) & 7;
        int cp = r >> 11;
        int j0 = js0 - 16 - cp;            // halfs e<4 use j0, e>=4 use j0+1
        const float* gb = grd + (((size_t)n * 32 + cq * 4) * 64 + i) * 64;
        h8 hv;
#pragma unroll
        for (int c = 0; c < 4; ++c) {
            float v0 = (j0 >= 0 && j0 < 64) ? gb[c * 4096 + j0] : 0.0f;
            float v1 = (j0 + 1 >= 0 && j0 + 1 < 64) ? gb[c * 4096 + j0 + 1] : 0.0f;
            hv[c]     = (_Float16)v0;
            hv[c + 4] = (_Float16)v1;
        }
        *(h8*)(g2 + (size_t)g * 8) = hv;
        return;
    }
    if (bx < G2V_BLOCKS + SH_BLOCKS) {
        int idx = (bx - G2V_BLOCKS) * 256 + tid;   // granule index < 524288
        int gr = idx & 31;
        int r  = (idx >> 5) & 63;
        int cq = (idx >> 11) & 7;
        int mm = idx >> 14;
        const float* sp = sat + (((size_t)mm * 32 + cq * 4) * 64 + r) * 64 + gr * 2;
        float2 v0 = *(const float2*)(sp);
        float2 v1 = *(const float2*)(sp + 4096);
        float2 v2 = *(const float2*)(sp + 8192);
        float2 v3 = *(const float2*)(sp + 12288);
        h8 hv = {(_Float16)v0.x, (_Float16)v1.x, (_Float16)v2.x, (_Float16)v3.x,
                 (_Float16)v0.y, (_Float16)v1.y, (_Float16)v2.y, (_Float16)v3.y};
        *(h8*)(sh + (size_t)idx * 8) = hv;
        return;
    }
    if (bx < G2V_BLOCKS + SH_BLOCKS + S2P_BLOCKS) {
        int blk = bx - G2V_BLOCKS - SH_BLOCKS;
        int m = blk >> 3, sl = blk & 7;
        int px0 = sl * 512 + tid * 2;              // 2 adjacent pixels/thread
        const float* base = sat + (size_t)m * SAMPLE_ELEMS + px0;
        float sA = 0.0f, sB = 0.0f;
        for (int c = 0; c < C_CH; ++c) {           // exact ascending-c order
            float2 v = *(const float2*)(base + c * 4096);
            sA += v.x * v.x;
            sB += v.y * v.y;
        }
        s2g[(size_t)m * 4096 + px0]     = sA;
        s2g[(size_t)m * 4096 + px0 + 1] = sB;
        return;
    }
    if (bx < G2V_BLOCKS + SH_BLOCKS + S2P_BLOCKS + N_GRD) {
        // grd norms
        const int b = bx - G2V_BLOCKS - SH_BLOCKS - S2P_BLOCKS;
        const float4* v = reinterpret_cast<const float4*>(grd + (size_t)b * SAMPLE_ELEMS);
        float ss = 0.0f;
        for (int p = tid; p < SAMPLE_ELEMS / 4; p += 256) {
            float4 q = v[p];
            ss += q.x * q.x + q.y * q.y + q.z * q.z + q.w * q.w;
        }
        for (int off = 32; off > 0; off >>= 1) ss += __shfl_down(ss, off);
        __shared__ float ls[4];
        int lane = tid & 63, w = tid >> 6;
        if (lane == 0) ls[w] = ss;
        __syncthreads();
        if (tid == 0)
            inv[b] = 1.0f / fmaxf(sqrtf(ls[0] + ls[1] + ls[2] + ls[3]), 1e-12f);
        return;
    }
    {   // zero partial + dots + cnt (float4)
        int idx = (bx - G2V_BLOCKS - SH_BLOCKS - S2P_BLOCKS - N_GRD) * 256 + tid;
        f4 z = {0.f, 0.f, 0.f, 0.f};
        if (idx < 204800)                 *(f4*)(partial + (size_t)idx * 4) = z;
        else if (idx - 204800 < 128)      *(f4*)(dots + (size_t)(idx - 204800) * 4) = z;
        else if (idx - 204800 == 128)     *(f4*)cntf = z;
    }
}

// ---------------------------------------------------------------------------
// K2: MFMA correlation (round-3 structure, best measured; UNCHANGED).
// Grid (m=32, xs=5, z=8: h=z&1, qt=z>>1); 4 waves = i.
// A staged per cqi via global_load_lds(16) from sh (zero-redirect padding),
// guarded by __syncthreads (2x per kernel).
// B is WAVE-PRIVATE: wave w only reads slices wi==w, so B staging needs no
// barrier.  Each wave stages its own 240 granules, double-buffered:
//    stage B(ii+1) -> s_waitcnt vmcnt(4) -> compute(ii)      [T3/T4]
// LDS = 48384 A + 2*15360 B = 79104 -> 2 blocks/CU.
// Output: fp32 atomicAdd into partial[m][n][xsl80][y80] (zeroed in prep).
// ---------------------------------------------------------------------------
__global__ __launch_bounds__(256, 2) void corr_mfma_kernel(const _Float16* __restrict__ sh,
                                                           const _Float16* __restrict__ g2,
                                                           float* __restrict__ partial) {
    __shared__ __align__(16) char lds[79104];
    char* AB = lds;                 // 48384
    char* BB = lds + 48384;         // 2 x 15360: [bsel][w4][cp2][n4][g30]x16B

    const int m  = blockIdx.x;
    const int xs = blockIdx.y;
    const int z  = blockIdx.z;
    const int h  = z & 1;
    const int qt = z >> 1;

    const int x00 = (xs < 4) ? 16 * xs : 49;
    const int qb  = (xs < 4) ? 16 * xs : 48;
    const int xoff = x00 - qb;
    const int qstage = qb + 40 * h;

    const int tid  = threadIdx.x;
    const int w    = tid >> 6;
    const int lane = tid & 63;
    const int s    = lane & 15;
    const int u    = lane >> 4;
    const int cp   = (s + xoff) & 1;

    f4 acc[5][4];
#pragma unroll
    for (int t = 0; t < 5; ++t)
#pragma unroll
        for (int n = 0; n < 4; ++n) { acc[t][n][0]=0.f; acc[t][n][1]=0.f; acc[t][n][2]=0.f; acc[t][n][3]=0.f; }

    const int woff = (16 - xoff + cp + 2 * u - s) * 8;
    const char* Blane = BB + w * 3840 + cp * 1920 + woff;
    const int abase0 = s * 336 + u * 16;
    const int q2base = qstage >> 1;

    size_t bsrc[4];
    bool bs_on[4];
#pragma unroll
    for (int k = 0; k < 4; ++k) {
        int idx = k * 64 + lane;
        bs_on[k] = idx < 240;
        int cpp = idx / 120; int rm = idx - cpp * 120;
        int nn = rm / 30;    int gg = rm - nn * 30;
        bsrc[k] = (size_t)cpp * 868352 + (size_t)nn * 424
                + (size_t)(gg + 20 * h) * 8 + (size_t)w * 27136;
    }

    auto stageA = [&](int cq) {
        for (int k = 0; k < 11; ++k) {
            int idx = k * 256 + tid;
            if (idx < 2688) {
                u32 r = (u32)idx / 21u;
                u32 g = (u32)idx - r * 21u;
                int q2 = q2base + (int)g;
                bool valid = (g < 20u) & (r >= 32u) & (r < 96u) & (q2 >= 16) & (q2 < 48);
                const _Float16* src = valid
                    ? sh + ((((size_t)m * 8 + cq) * 64 + (r - 32)) * 32 + (q2 - 16)) * 8
                    : g2;   // first granules of g2 are structurally zero
                __builtin_amdgcn_global_load_lds(
                    (const __attribute__((address_space(1))) u32*)(const void*)src,
                    (__attribute__((address_space(3))) u32*)(void*)(AB + k * 4096 + w * 1024),
                    16, 0, 0);
            }
        }
    };

    auto stageB = [&](int cq, int ii, int bsel) {
        asm volatile("s_waitcnt lgkmcnt(0)" ::: "memory");
        char* dst0 = BB + bsel * 15360 + w * 3840;
        const size_t add = (size_t)cq * 108544 + (size_t)ii * 1696;
#pragma unroll
        for (int k = 0; k < 4; ++k) {
            if (bs_on[k])
                __builtin_amdgcn_global_load_lds(
                    (const __attribute__((address_space(1))) u32*)(const void*)(g2 + bsrc[k] + add),
                    (__attribute__((address_space(3))) u32*)(void*)(dst0 + k * 1024),
                    16, 0, 0);
        }
    };

    auto compute = [&](int ii, int bsel) {
        const char* Ab = AB + abase0 + (w * 16 + ii) * 336;
        const char* Bb = Blane + bsel * 15360;
#pragma unroll
        for (int qs = 0; qs < 5; ++qs) {
            h8 a[5]; h8 bfr[4];
#pragma unroll
            for (int n = 0; n < 4; ++n) bfr[n] = *(const h8*)(Bb + qs * 64 + n * 480);
#pragma unroll
            for (int t = 0; t < 5; ++t) a[t] = *(const h8*)(Ab + qs * 64 + t * 5376);
#pragma unroll
            for (int t = 0; t < 5; ++t)
#pragma unroll
                for (int n = 0; n < 4; ++n)
                    acc[t][n] = __builtin_amdgcn_mfma_f32_16x16x32_f16(a[t], bfr[n], acc[t][n], 0, 0, 0);
        }
    };

    for (int cqi = 0; cqi < 2; ++cqi) {
        const int cq = qt * 2 + cqi;
        __syncthreads();          // prior readers of AB/BB done
        stageA(cq);
        stageB(cq, 0, 0);
        __syncthreads();          // full drain: A + B(0) resident
#pragma unroll 1
        for (int iip = 0; iip < 8; ++iip) {
            const int ii0 = 2 * iip;
            stageB(cq, ii0 + 1, 1);
            asm volatile("s_waitcnt vmcnt(4)" ::: "memory");
            compute(ii0, 0);
            if (iip < 7) {
                stageB(cq, ii0 + 2, 0);
                asm volatile("s_waitcnt vmcnt(4)" ::: "memory");
            } else {
                asm volatile("s_waitcnt vmcnt(0)" ::: "memory");
            }
            compute(ii0 + 1, 1);
        }
    }

    // ---- cross-wave (i) reduce in LDS, then atomicAdd into partial
    float* red = (float*)lds;
#pragma unroll
    for (int t = 0; t < 5; ++t) {
        __syncthreads();
#pragma unroll
        for (int nn = 0; nn < 4; ++nn)
            *(f4*)(red + ((nn * 4 + w) * 64 + lane) * 4) = acc[t][nn];
        __syncthreads();
        {
            int nn = tid >> 6, ln = tid & 63;
            f4 sum = *(f4*)(red + ((nn * 4 + 0) * 64 + ln) * 4);
            sum = sum + *(f4*)(red + ((nn * 4 + 1) * 64 + ln) * 4);
            sum = sum + *(f4*)(red + ((nn * 4 + 2) * 64 + ln) * 4);
            sum = sum + *(f4*)(red + ((nn * 4 + 3) * 64 + ln) * 4);
            int ss = ln & 15, uu = ln >> 4;
            float* dst = partial + ((size_t)(m * 4 + nn)) * 6400
                         + (xs * 16 + ss) * 80 + t * 16 + uu * 4;
#pragma unroll
            for (int l = 0; l < 4; ++l) atomicAdd(dst + l, sum[l]);
        }
    }
}

// ---------------------------------------------------------------------------
// K3: epilogue.  Builds the per-m prefix SAT in LDS from s2g (scan order
// bit-identical to the old prep SAT), computes inv_sat locally; n==0 block
// persists S[m] + inv[4+m] for the refine kernel (next launch -> ordered).
// Then normalize + top-4 candidates per (m,n).
// ---------------------------------------------------------------------------
__global__ __launch_bounds__(256) void epilogue_kernel(const float* __restrict__ partial,
                                                       const float* __restrict__ s2g,
                                                       float* __restrict__ S,
                                                       float* __restrict__ inv,
                                                       const int* __restrict__ unc,
                                                       float* __restrict__ candv,
                                                       int* __restrict__ candi) {
    const int b = blockIdx.x;
    const int m = b >> 2, n = b & 3;
    const int tid = threadIdx.x;
    __shared__ float P[64][65];

    // build prefix SAT (exact replica of old prep scans)
    const float* sg = s2g + (size_t)m * 4096;
    for (int idx = tid; idx < 4096; idx += 256) P[idx >> 6][idx & 63] = sg[idx];
    __syncthreads();
    if (tid < 64) {
        int r = tid; float run = 0.0f;
        for (int w = 0; w < 64; ++w) { run += P[r][w]; P[r][w] = run; }
    }
    __syncthreads();
    if (tid < 64) {
        int c = tid; float run = 0.0f;
        for (int h = 0; h < 64; ++h) { run += P[h][c]; P[h][c] = run; }
    }
    __syncthreads();
    const float isn = 1.0f / fmaxf(sqrtf(P[63][63]), 1e-12f);
    if (n == 0) {
        if (tid == 0) inv[N_GRD + m] = isn;
        float* Sm = S + (size_t)m * (HO * WO);
        for (int p = tid; p < HO * WO; p += 256) {
            int r = p / 65, c = p - r * 65;
            Sm[p] = (r == 0 || c == 0) ? 0.0f : P[r - 1][c - 1];
        }
    }

    const float uu = (float)unc[0];
    const float sc = inv[n] * isn;
    const float* pb = partial + (size_t)(m * 4 + n) * 6400;

    float best = -3.4e38f;
    int bidx = 0x7fffffff;
    for (int pp = tid; pp < 4225; pp += 256) {
        int x = pp / 65, y = pp - x * 65;
        int xsl = (x == 64) ? 79 : x;
        float raw = pb[xsl * 80 + y];
        float num = raw * sc;
        int r0 = max(0, y - 32), r1 = min(64, y + 32);
        int q0 = max(0, x - 32), q1 = min(64, x + 32);
        float s11 = P[r1 - 1][q1 - 1];
        float s01 = (r0 == 0) ? 0.0f : P[r0 - 1][q1 - 1];
        float s10 = (q0 == 0) ? 0.0f : P[r1 - 1][q0 - 1];
        float s00 = (r0 == 0 || q0 == 0) ? 0.0f : P[r0 - 1][q0 - 1];
        float ps = s11 - s01 - s10 + s00;
        float denom = fmaxf(sqrtf(ps) * isn * uu, 1e-12f);
        float v = num / denom;
        int p = y * 65 + x;
        if (v > best || (v == best && p < bidx)) { best = v; bidx = p; }
    }
    __shared__ float bv[256]; __shared__ int bi[256];
    __shared__ float cv[256]; __shared__ int ci[256];
    __shared__ int winner;
    bv[tid] = best; bi[tid] = bidx;
    __syncthreads();
    for (int round = 0; round < 4; ++round) {
        cv[tid] = bv[tid]; ci[tid] = bi[tid];
        __syncthreads();
        for (int st = 128; st > 0; st >>= 1) {
            if (tid < st) {
                float ov = cv[tid + st]; int oi = ci[tid + st];
                if (ov > cv[tid] || (ov == cv[tid] && oi < ci[tid])) { cv[tid] = ov; ci[tid] = oi; }
            }
            __syncthreads();
        }
        if (tid == 0) { candv[b * 4 + round] = cv[0]; candi[b * 4 + round] = ci[0]; winner = ci[0]; }
        __syncthreads();
        if (bi[tid] == winner) bv[tid] = -3.4e38f;
        __syncthreads();
    }
}

// ---------------------------------------------------------------------------
// K4: refine_dot + fused last-block pick.  Grid (128 b, 4 k, 8 cq).
// Every block (including skipped ones) increments cnt after threadfence;
// the 4096th block sees all dots atomics and runs the 128-wide pick,
// writing the final outputs (replaces the old refine_pick launch).
// ---------------------------------------------------------------------------
__global__ __launch_bounds__(256) void refine_dot_kernel(const float* __restrict__ grd,
                                                         const float* __restrict__ sat,
                                                         const float* __restrict__ candv,
                                                         const int* __restrict__ candi,
                                                         float* __restrict__ dots,
                                                         const float* __restrict__ S,
                                                         const float* __restrict__ inv,
                                                         const int* __restrict__ unc,
                                                         unsigned* __restrict__ cnt,
                                                         float* __restrict__ out) {
    const int b = blockIdx.x;
    const int k = blockIdx.y;
    const int cq = blockIdx.z;
    const int m = b >> 2, n = b & 3;
    const int tid = threadIdx.x, lane = tid & 63, w = tid >> 6;
    __shared__ float ls[4];
    __shared__ int lastf;

    float v0 = candv[b * 4];
    float thr = v0 - (0.02f * fabsf(v0) + 1e-4f);
    bool skip = (k > 0 && candv[b * 4 + k] < thr);
    if (!skip) {
        int p = candi[b * 4 + k];
        int y = p / 65, x = p - y * 65;
        const int ilo = max(0, 32 - y), ihi = min(64, 96 - y);
        int xj = x + lane - 32;
        float acc = 0.0f;
        if (xj >= 0 && xj < 64) {
            const float* sm = sat + (size_t)m * SAMPLE_ELEMS;
            const float* gn = grd + (size_t)n * SAMPLE_ELEMS;
            for (int cc = 0; cc < 4; ++cc) {
                const int cbase = (cq * 4 + cc) << 12;
                const float* sp = sm + cbase + xj + ((y - 32) << 6);
                const float* gp = gn + cbase + lane;
                for (int i = ilo + w; i < ihi; i += 4)
                    acc = fmaf(sp[i << 6], gp[i << 6], acc);
            }
        }
        for (int off = 32; off > 0; off >>= 1) acc += __shfl_down(acc, off);
        if (lane == 0) ls[w] = acc;
        __syncthreads();
        if (tid == 0) atomicAdd(&dots[b * 4 + k], ls[0] + ls[1] + ls[2] + ls[3]);
    }

    // ---- completion count; last block runs the pick
    __syncthreads();
    if (tid == 0) {
        __threadfence();
        unsigned prev = atomicAdd(cnt, 1u);
        lastf = (prev == 128u * 4u * 8u - 1u) ? 1 : 0;
    }
    __syncthreads();
    if (!lastf) return;
    __threadfence();
    if (tid >= 128) return;
    {
        const int bb = tid;
        const int mm = bb >> 2, nn = bb & 3;
        const volatile float* dv = dots;
        const float uu = (float)unc[0];
        const float scp = inv[nn] * inv[N_GRD + mm];
        const float isn = inv[N_GRD + mm];
        const float* Sm = S + (size_t)mm * 4225;
        float w0 = candv[bb * 4];
        float thr2 = w0 - (0.02f * fabsf(w0) + 1e-4f);
        float bestv = -3.4e38f; int bestp = 0x7fffffff;
        for (int kk = 0; kk < 4; ++kk) {
            if (kk > 0 && candv[bb * 4 + kk] < thr2) break;   // candv sorted desc
            int p = candi[bb * 4 + kk];
            int y = p / 65, x = p - y * 65;
            int r0 = max(0, y - 32), r1 = min(64, y + 32);
            int q0 = max(0, x - 32), q1 = min(64, x + 32);
            float ps = Sm[r1 * 65 + q1] - Sm[r0 * 65 + q1] - Sm[r1 * 65 + q0] + Sm[r0 * 65 + q0];
            float denom = fmaxf(sqrtf(ps) * isn * uu, 1e-12f);
            float v = dv[bb * 4 + kk] * scp / denom;
            if (v > bestv || (v == bestv && p < bestp)) { bestv = v; bestp = p; }
        }
        out[bb] = bestv;
        int row = bestp / 65, col = bestp - row * 65;
        float pr = -((float)row - 32.5f);
        float pc = (float)col - 32.5f;
        out[128 + bb * 2 + 0] = ((pr * 0.2f) * 512.0f) * (1.0f / 128.0f);
        out[128 + bb * 2 + 1] = ((pc * 0.2f) * 512.0f) * (1.0f / 128.0f);
    }
}

// ---------------------------------------------------------------------------
extern "C" void kernel_launch(void* const* d_in, const int* in_sizes, int n_in,
                              void* d_out, int out_size, void* d_ws, size_t ws_size,
                              hipStream_t stream) {
    const float* grd = (const float*)d_in[0];
    const float* sat = (const float*)d_in[1];
    const int*   unc = (const int*)d_in[2];
    float* out = (float*)d_out;
    float* ws  = (float*)d_ws;

    float* inv     = ws + OFF_INV;
    float* cntf    = ws + 48;                     // 16B scratch in inv block
    float* S       = ws + OFF_S;
    float* candv   = ws + OFF_CANDV;
    int*   candi   = (int*)(ws + OFF_CANDI);
    float* dots    = ws + OFF_DOTS;
    float* partial = ws + OFF_PART;
    _Float16* g2   = (_Float16*)(ws + OFF_G2F);
    _Float16* sh   = (_Float16*)(ws + OFF_SH);
    float* s2g     = ws + OFF_S2G;                // ~16.2 MB total ws use

    prep_kernel<<<PREP_BLOCKS, 256, 0, stream>>>(grd, sat, g2, sh, s2g, inv, partial, dots, cntf);
    corr_mfma_kernel<<<dim3(M_SAT, 5, 8), 256, 0, stream>>>(sh, g2, partial);
    epilogue_kernel<<<M_SAT * N_GRD, 256, 0, stream>>>(partial, s2g, S, inv, unc, candv, candi);
    refine_dot_kernel<<<dim3(128, 4, 8), 256, 0, stream>>>(grd, sat, candv, candi, dots,
                                                           S, inv, unc, (unsigned*)cntf, out);
}

// Round 8
// 427.364 us; speedup vs baseline: 1.0030x; 1.0030x over previous
//
#include <hip/hip_runtime.h>
#include <math.h>

#define N_GRD 4
#define M_SAT 32
#define C_CH  32
#define HK    64
#define WK    64
#define HO    65
#define WO    65
#define SAMPLE_ELEMS (C_CH * HK * WK)

typedef _Float16 h8 __attribute__((ext_vector_type(8)));
typedef float    f4 __attribute__((ext_vector_type(4)));
typedef unsigned int u32;

// ---- ws layout (float units) ----
#define OFF_INV    0                  // inv[0..35]
#define OFF_S      64                 // 32 * 4225
#define OFF_CANDV  135264
#define OFF_CANDI  135776
#define OFF_DOTS   136288             // 512
#define OFF_PART   136800             // 32 m * 4 n * 80 xsl * 80 y = 819200
#define OFF_G2F    956000             // G2_HALFS/2 floats
#define OFF_SH     1824352            // 524288 granules * 8 halfs = 2097152 floats
#define OFF_S2G    3921504            // 32 m * 4096 raw squared-norm sums
#define OFF_CNT    4052576            // 128 counters padded to 16 uints each
#define G2_HALFS   1736704            // 2cp * 8cq * 64i * 4n * 106js * 4c

#define G2V_BLOCKS 848                // G2_HALFS/8 granules / 256
#define SH_BLOCKS  2048               // 524288/256
#define S2P_BLOCKS 256                // 32 m x 8 slices of 512 px (exact s2)
#define ZERO_BLOCKS 803               // partial 204800 + dots 128 + cnt 512 f4
#define PREP_BLOCKS (G2V_BLOCKS + SH_BLOCKS + S2P_BLOCKS + N_GRD + ZERO_BLOCKS)

// ---------------------------------------------------------------------------
// K1 (fused prep), by blockIdx range:
//  [0,848)         g2 Toeplitz build, vectorized (1 thread = 1 granule)
//  [848,2896)      sh build: fp16 sat in DMA-granule layout (16B stores)
//  [2896,3152)     s2g: per-pixel sum over 32 channels of sat^2, EXACT serial
//                  ascending-c order (bit-identical to old SAT phase 1)
//  [3152,3156)     grd inv-norms
//  [3156,3959)     zero partial + dots + per-b completion counters
// ---------------------------------------------------------------------------
__global__ __launch_bounds__(256) void prep_kernel(const float* __restrict__ grd,
                                                   const float* __restrict__ sat,
                                                   _Float16* __restrict__ g2,
                                                   _Float16* __restrict__ sh,
                                                   float* __restrict__ s2g,
                                                   float* __restrict__ inv,
                                                   float* __restrict__ partial,
                                                   float* __restrict__ dots,
                                                   float* __restrict__ cntf) {
    const int bx = blockIdx.x;
    const int tid = threadIdx.x;

    if (bx < G2V_BLOCKS) {
        int g = bx * 256 + tid;            // granule index < 217088
        int t0 = g * 2;
        int js0 = t0 % 106;
        int r = t0 / 106;
        int n  = r & 3;
        int i  = (r >> 2) & 63;
        int cq = (r >> 8) & 7;
        int cp = r >> 11;
        int j0 = js0 - 16 - cp;            // halfs e<4 use j0, e>=4 use j0+1
        const float* gb = grd + (((size_t)n * 32 + cq * 4) * 64 + i) * 64;
        h8 hv;
#pragma unroll
        for (int c = 0; c < 4; ++c) {
            float v0 = (j0 >= 0 && j0 < 64) ? gb[c * 4096 + j0] : 0.0f;
            float v1 = (j0 + 1 >= 0 && j0 + 1 < 64) ? gb[c * 4096 + j0 + 1] : 0.0f;
            hv[c]     = (_Float16)v0;
            hv[c + 4] = (_Float16)v1;
        }
        *(h8*)(g2 + (size_t)g * 8) = hv;
        return;
    }
    if (bx < G2V_BLOCKS + SH_BLOCKS) {
        int idx = (bx - G2V_BLOCKS) * 256 + tid;   // granule index < 524288
        int gr = idx & 31;
        int r  = (idx >> 5) & 63;
        int cq = (idx >> 11) & 7;
        int mm = idx >> 14;
        const float* sp = sat + (((size_t)mm * 32 + cq * 4) * 64 + r) * 64 + gr * 2;
        float2 v0 = *(const float2*)(sp);
        float2 v1 = *(const float2*)(sp + 4096);
        float2 v2 = *(const float2*)(sp + 8192);
        float2 v3 = *(const float2*)(sp + 12288);
        h8 hv = {(_Float16)v0.x, (_Float16)v1.x, (_Float16)v2.x, (_Float16)v3.x,
                 (_Float16)v0.y, (_Float16)v1.y, (_Float16)v2.y, (_Float16)v3.y};
        *(h8*)(sh + (size_t)idx * 8) = hv;
        return;
    }
    if (bx < G2V_BLOCKS + SH_BLOCKS + S2P_BLOCKS) {
        int blk = bx - G2V_BLOCKS - SH_BLOCKS;
        int m = blk >> 3, sl = blk & 7;
        int px0 = sl * 512 + tid * 2;              // 2 adjacent pixels/thread
        const float* base = sat + (size_t)m * SAMPLE_ELEMS + px0;
        float sA = 0.0f, sB = 0.0f;
        for (int c = 0; c < C_CH; ++c) {           // exact ascending-c order
            float2 v = *(const float2*)(base + c * 4096);
            sA += v.x * v.x;
            sB += v.y * v.y;
        }
        s2g[(size_t)m * 4096 + px0]     = sA;
        s2g[(size_t)m * 4096 + px0 + 1] = sB;
        return;
    }
    if (bx < G2V_BLOCKS + SH_BLOCKS + S2P_BLOCKS + N_GRD) {
        // grd norms
        const int b = bx - G2V_BLOCKS - SH_BLOCKS - S2P_BLOCKS;
        const float4* v = reinterpret_cast<const float4*>(grd + (size_t)b * SAMPLE_ELEMS);
        float ss = 0.0f;
        for (int p = tid; p < SAMPLE_ELEMS / 4; p += 256) {
            float4 q = v[p];
            ss += q.x * q.x + q.y * q.y + q.z * q.z + q.w * q.w;
        }
        for (int off = 32; off > 0; off >>= 1) ss += __shfl_down(ss, off);
        __shared__ float ls[4];
        int lane = tid & 63, w = tid >> 6;
        if (lane == 0) ls[w] = ss;
        __syncthreads();
        if (tid == 0)
            inv[b] = 1.0f / fmaxf(sqrtf(ls[0] + ls[1] + ls[2] + ls[3]), 1e-12f);
        return;
    }
    {   // zero partial + dots + counters (float4)
        int idx = (bx - G2V_BLOCKS - SH_BLOCKS - S2P_BLOCKS - N_GRD) * 256 + tid;
        f4 z = {0.f, 0.f, 0.f, 0.f};
        if (idx < 204800)                 *(f4*)(partial + (size_t)idx * 4) = z;
        else if (idx - 204800 < 128)      *(f4*)(dots + (size_t)(idx - 204800) * 4) = z;
        else if (idx - 204928 < 512)      *(f4*)(cntf + (size_t)(idx - 204928) * 4) = z;
    }
}

// ---------------------------------------------------------------------------
// K2: MFMA correlation (round-3 structure, best measured; UNCHANGED).
// Grid (m=32, xs=5, z=8: h=z&1, qt=z>>1); 4 waves = i.
// A staged per cqi via global_load_lds(16) from sh (zero-redirect padding),
// guarded by __syncthreads (2x per kernel).
// B is WAVE-PRIVATE: wave w only reads slices wi==w, so B staging needs no
// barrier.  Each wave stages its own 240 granules, double-buffered:
//    stage B(ii+1) -> s_waitcnt vmcnt(4) -> compute(ii)      [T3/T4]
// LDS = 48384 A + 2*15360 B = 79104 -> 2 blocks/CU.
// Output: fp32 atomicAdd into partial[m][n][xsl80][y80] (zeroed in prep).
// ---------------------------------------------------------------------------
__global__ __launch_bounds__(256, 2) void corr_mfma_kernel(const _Float16* __restrict__ sh,
                                                           const _Float16* __restrict__ g2,
                                                           float* __restrict__ partial) {
    __shared__ __align__(16) char lds[79104];
    char* AB = lds;                 // 48384
    char* BB = lds + 48384;         // 2 x 15360: [bsel][w4][cp2][n4][g30]x16B

    const int m  = blockIdx.x;
    const int xs = blockIdx.y;
    const int z  = blockIdx.z;
    const int h  = z & 1;
    const int qt = z >> 1;

    const int x00 = (xs < 4) ? 16 * xs : 49;
    const int qb  = (xs < 4) ? 16 * xs : 48;
    const int xoff = x00 - qb;
    const int qstage = qb + 40 * h;

    const int tid  = threadIdx.x;
    const int w    = tid >> 6;
    const int lane = tid & 63;
    const int s    = lane & 15;
    const int u    = lane >> 4;
    const int cp   = (s + xoff) & 1;

    f4 acc[5][4];
#pragma unroll
    for (int t = 0; t < 5; ++t)
#pragma unroll
        for (int n = 0; n < 4; ++n) { acc[t][n][0]=0.f; acc[t][n][1]=0.f; acc[t][n][2]=0.f; acc[t][n][3]=0.f; }

    const int woff = (16 - xoff + cp + 2 * u - s) * 8;
    const char* Blane = BB + w * 3840 + cp * 1920 + woff;
    const int abase0 = s * 336 + u * 16;
    const int q2base = qstage >> 1;

    size_t bsrc[4];
    bool bs_on[4];
#pragma unroll
    for (int k = 0; k < 4; ++k) {
        int idx = k * 64 + lane;
        bs_on[k] = idx < 240;
        int cpp = idx / 120; int rm = idx - cpp * 120;
        int nn = rm / 30;    int gg = rm - nn * 30;
        bsrc[k] = (size_t)cpp * 868352 + (size_t)nn * 424
                + (size_t)(gg + 20 * h) * 8 + (size_t)w * 27136;
    }

    auto stageA = [&](int cq) {
        for (int k = 0; k < 11; ++k) {
            int idx = k * 256 + tid;
            if (idx < 2688) {
                u32 r = (u32)idx / 21u;
                u32 g = (u32)idx - r * 21u;
                int q2 = q2base + (int)g;
                bool valid = (g < 20u) & (r >= 32u) & (r < 96u) & (q2 >= 16) & (q2 < 48);
                const _Float16* src = valid
                    ? sh + ((((size_t)m * 8 + cq) * 64 + (r - 32)) * 32 + (q2 - 16)) * 8
                    : g2;   // first granules of g2 are structurally zero
                __builtin_amdgcn_global_load_lds(
                    (const __attribute__((address_space(1))) u32*)(const void*)src,
                    (__attribute__((address_space(3))) u32*)(void*)(AB + k * 4096 + w * 1024),
                    16, 0, 0);
            }
        }
    };

    auto stageB = [&](int cq, int ii, int bsel) {
        asm volatile("s_waitcnt lgkmcnt(0)" ::: "memory");
        char* dst0 = BB + bsel * 15360 + w * 3840;
        const size_t add = (size_t)cq * 108544 + (size_t)ii * 1696;
#pragma unroll
        for (int k = 0; k < 4; ++k) {
            if (bs_on[k])
                __builtin_amdgcn_global_load_lds(
                    (const __attribute__((address_space(1))) u32*)(const void*)(g2 + bsrc[k] + add),
                    (__attribute__((address_space(3))) u32*)(void*)(dst0 + k * 1024),
                    16, 0, 0);
        }
    };

    auto compute = [&](int ii, int bsel) {
        const char* Ab = AB + abase0 + (w * 16 + ii) * 336;
        const char* Bb = Blane + bsel * 15360;
#pragma unroll
        for (int qs = 0; qs < 5; ++qs) {
            h8 a[5]; h8 bfr[4];
#pragma unroll
            for (int n = 0; n < 4; ++n) bfr[n] = *(const h8*)(Bb + qs * 64 + n * 480);
#pragma unroll
            for (int t = 0; t < 5; ++t) a[t] = *(const h8*)(Ab + qs * 64 + t * 5376);
#pragma unroll
            for (int t = 0; t < 5; ++t)
#pragma unroll
                for (int n = 0; n < 4; ++n)
                    acc[t][n] = __builtin_amdgcn_mfma_f32_16x16x32_f16(a[t], bfr[n], acc[t][n], 0, 0, 0);
        }
    };

    for (int cqi = 0; cqi < 2; ++cqi) {
        const int cq = qt * 2 + cqi;
        __syncthreads();          // prior readers of AB/BB done
        stageA(cq);
        stageB(cq, 0, 0);
        __syncthreads();          // full drain: A + B(0) resident
#pragma unroll 1
        for (int iip = 0; iip < 8; ++iip) {
            const int ii0 = 2 * iip;
            stageB(cq, ii0 + 1, 1);
            asm volatile("s_waitcnt vmcnt(4)" ::: "memory");
            compute(ii0, 0);
            if (iip < 7) {
                stageB(cq, ii0 + 2, 0);
                asm volatile("s_waitcnt vmcnt(4)" ::: "memory");
            } else {
                asm volatile("s_waitcnt vmcnt(0)" ::: "memory");
            }
            compute(ii0 + 1, 1);
        }
    }

    // ---- cross-wave (i) reduce in LDS, then atomicAdd into partial
    float* red = (float*)lds;
#pragma unroll
    for (int t = 0; t < 5; ++t) {
        __syncthreads();
#pragma unroll
        for (int nn = 0; nn < 4; ++nn)
            *(f4*)(red + ((nn * 4 + w) * 64 + lane) * 4) = acc[t][nn];
        __syncthreads();
        {
            int nn = tid >> 6, ln = tid & 63;
            f4 sum = *(f4*)(red + ((nn * 4 + 0) * 64 + ln) * 4);
            sum = sum + *(f4*)(red + ((nn * 4 + 1) * 64 + ln) * 4);
            sum = sum + *(f4*)(red + ((nn * 4 + 2) * 64 + ln) * 4);
            sum = sum + *(f4*)(red + ((nn * 4 + 3) * 64 + ln) * 4);
            int ss = ln & 15, uu = ln >> 4;
            float* dst = partial + ((size_t)(m * 4 + nn)) * 6400
                         + (xs * 16 + ss) * 80 + t * 16 + uu * 4;
#pragma unroll
            for (int l = 0; l < 4; ++l) atomicAdd(dst + l, sum[l]);
        }
    }
}

// ---------------------------------------------------------------------------
// K3: epilogue.  Builds the per-m prefix SAT in LDS from s2g (scan order
// bit-identical to the original), computes inv_sat locally; n==0 block
// persists S[m] + inv[4+m] for the refine kernel (next launch -> ordered).
// Then normalize + top-4 candidates per (m,n).
// ---------------------------------------------------------------------------
__global__ __launch_bounds__(256) void epilogue_kernel(const float* __restrict__ partial,
                                                       const float* __restrict__ s2g,
                                                       float* __restrict__ S,
                                                       float* __restrict__ inv,
                                                       const int* __restrict__ unc,
                                                       float* __restrict__ candv,
                                                       int* __restrict__ candi) {
    const int b = blockIdx.x;
    const int m = b >> 2, n = b & 3;
    const int tid = threadIdx.x;
    __shared__ float P[64][65];

    // build prefix SAT (exact replica of original scans)
    const float* sg = s2g + (size_t)m * 4096;
    for (int idx = tid; idx < 4096; idx += 256) P[idx >> 6][idx & 63] = sg[idx];
    __syncthreads();
    if (tid < 64) {
        int r = tid; float run = 0.0f;
        for (int w = 0; w < 64; ++w) { run += P[r][w]; P[r][w] = run; }
    }
    __syncthreads();
    if (tid < 64) {
        int c = tid; float run = 0.0f;
        for (int h = 0; h < 64; ++h) { run += P[h][c]; P[h][c] = run; }
    }
    __syncthreads();
    const float isn = 1.0f / fmaxf(sqrtf(P[63][63]), 1e-12f);
    if (n == 0) {
        if (tid == 0) inv[N_GRD + m] = isn;
        float* Sm = S + (size_t)m * (HO * WO);
        for (int p = tid; p < HO * WO; p += 256) {
            int r = p / 65, c = p - r * 65;
            Sm[p] = (r == 0 || c == 0) ? 0.0f : P[r - 1][c - 1];
        }
    }

    const float uu = (float)unc[0];
    const float sc = inv[n] * isn;
    const float* pb = partial + (size_t)(m * 4 + n) * 6400;

    float best = -3.4e38f;
    int bidx = 0x7fffffff;
    for (int pp = tid; pp < 4225; pp += 256) {
        int x = pp / 65, y = pp - x * 65;
        int xsl = (x == 64) ? 79 : x;
        float raw = pb[xsl * 80 + y];
        float num = raw * sc;
        int r0 = max(0, y - 32), r1 = min(64, y + 32);
        int q0 = max(0, x - 32), q1 = min(64, x + 32);
        float s11 = P[r1 - 1][q1 - 1];
        float s01 = (r0 == 0) ? 0.0f : P[r0 - 1][q1 - 1];
        float s10 = (q0 == 0) ? 0.0f : P[r1 - 1][q0 - 1];
        float s00 = (r0 == 0 || q0 == 0) ? 0.0f : P[r0 - 1][q0 - 1];
        float ps = s11 - s01 - s10 + s00;
        float denom = fmaxf(sqrtf(ps) * isn * uu, 1e-12f);
        float v = num / denom;
        int p = y * 65 + x;
        if (v > best || (v == best && p < bidx)) { best = v; bidx = p; }
    }
    __shared__ float bv[256]; __shared__ int bi[256];
    __shared__ float cv[256]; __shared__ int ci[256];
    __shared__ int winner;
    bv[tid] = best; bi[tid] = bidx;
    __syncthreads();
    for (int round = 0; round < 4; ++round) {
        cv[tid] = bv[tid]; ci[tid] = bi[tid];
        __syncthreads();
        for (int st = 128; st > 0; st >>= 1) {
            if (tid < st) {
                float ov = cv[tid + st]; int oi = ci[tid + st];
                if (ov > cv[tid] || (ov == cv[tid] && oi < ci[tid])) { cv[tid] = ov; ci[tid] = oi; }
            }
            __syncthreads();
        }
        if (tid == 0) { candv[b * 4 + round] = cv[0]; candi[b * 4 + round] = ci[0]; winner = ci[0]; }
        __syncthreads();
        if (bi[tid] == winner) bv[tid] = -3.4e38f;
        __syncthreads();
    }
}

// ---------------------------------------------------------------------------
// K4: refine_dot + distributed last-block pick.  Grid (128 b, 4 k, 8 cq).
// Each block fences + increments its b's PADDED counter (cnt[b*16], one
// cacheline per b -> 32 atomics x 128 independent lines, no serialization).
// The block seeing prev==31 for its b runs the 4-candidate pick for that b
// on one thread (replaces the old refine_pick launch).
// ---------------------------------------------------------------------------
__global__ __launch_bounds__(256) void refine_dot_kernel(const float* __restrict__ grd,
                                                         const float* __restrict__ sat,
                                                         const float* __restrict__ candv,
                                                         const int* __restrict__ candi,
                                                         float* __restrict__ dots,
                                                         const float* __restrict__ S,
                                                         const float* __restrict__ inv,
                                                         const int* __restrict__ unc,
                                                         unsigned* __restrict__ cnt,
                                                         float* __restrict__ out) {
    const int b = blockIdx.x;
    const int k = blockIdx.y;
    const int cq = blockIdx.z;
    const int m = b >> 2, n = b & 3;
    const int tid = threadIdx.x, lane = tid & 63, w = tid >> 6;
    __shared__ float ls[4];
    __shared__ int lastf;

    float v0 = candv[b * 4];
    float thr = v0 - (0.02f * fabsf(v0) + 1e-4f);
    bool skip = (k > 0 && candv[b * 4 + k] < thr);
    if (!skip) {
        int p = candi[b * 4 + k];
        int y = p / 65, x = p - y * 65;
        const int ilo = max(0, 32 - y), ihi = min(64, 96 - y);
        int xj = x + lane - 32;
        float acc = 0.0f;
        if (xj >= 0 && xj < 64) {
            const float* sm = sat + (size_t)m * SAMPLE_ELEMS;
            const float* gn = grd + (size_t)n * SAMPLE_ELEMS;
            for (int cc = 0; cc < 4; ++cc) {
                const int cbase = (cq * 4 + cc) << 12;
                const float* sp = sm + cbase + xj + ((y - 32) << 6);
                const float* gp = gn + cbase + lane;
                for (int i = ilo + w; i < ihi; i += 4)
                    acc = fmaf(sp[i << 6], gp[i << 6], acc);
            }
        }
        for (int off = 32; off > 0; off >>= 1) acc += __shfl_down(acc, off);
        if (lane == 0) ls[w] = acc;
        __syncthreads();
        if (tid == 0) atomicAdd(&dots[b * 4 + k], ls[0] + ls[1] + ls[2] + ls[3]);
    }

    // ---- per-b completion count; last block of this b runs its pick
    __syncthreads();
    if (tid == 0) {
        __threadfence();
        unsigned prev = atomicAdd(&cnt[(size_t)b * 16], 1u);
        lastf = (prev == 31u) ? 1 : 0;
    }
    __syncthreads();
    if (!lastf) return;
    if (tid != 0) return;
    {
        __threadfence();
        const volatile float* dv = dots;
        const float uu = (float)unc[0];
        const float scp = inv[n] * inv[N_GRD + m];
        const float isn = inv[N_GRD + m];
        const float* Sm = S + (size_t)m * 4225;
        float bestv = -3.4e38f; int bestp = 0x7fffffff;
        for (int kk = 0; kk < 4; ++kk) {
            if (kk > 0 && candv[b * 4 + kk] < thr) break;   // candv sorted desc
            int p = candi[b * 4 + kk];
            int y = p / 65, x = p - y * 65;
            int r0 = max(0, y - 32), r1 = min(64, y + 32);
            int q0 = max(0, x - 32), q1 = min(64, x + 32);
            float ps = Sm[r1 * 65 + q1] - Sm[r0 * 65 + q1] - Sm[r1 * 65 + q0] + Sm[r0 * 65 + q0];
            float denom = fmaxf(sqrtf(ps) * isn * uu, 1e-12f);
            float v = dv[b * 4 + kk] * scp / denom;
            if (v > bestv || (v == bestv && p < bestp)) { bestv = v; bestp = p; }
        }
        out[b] = bestv;
        int row = bestp / 65, col = bestp - row * 65;
        float pr = -((float)row - 32.5f);
        float pc = (float)col - 32.5f;
        out[128 + b * 2 + 0] = ((pr * 0.2f) * 512.0f) * (1.0f / 128.0f);
        out[128 + b * 2 + 1] = ((pc * 0.2f) * 512.0f) * (1.0f / 128.0f);
    }
}

// ---------------------------------------------------------------------------
extern "C" void kernel_launch(void* const* d_in, const int* in_sizes, int n_in,
                              void* d_out, int out_size, void* d_ws, size_t ws_size,
                              hipStream_t stream) {
    const float* grd = (const float*)d_in[0];
    const float* sat = (const float*)d_in[1];
    const int*   unc = (const int*)d_in[2];
    float* out = (float*)d_out;
    float* ws  = (float*)d_ws;

    float* inv     = ws + OFF_INV;
    float* S       = ws + OFF_S;
    float* candv   = ws + OFF_CANDV;
    int*   candi   = (int*)(ws + OFF_CANDI);
    float* dots    = ws + OFF_DOTS;
    float* partial = ws + OFF_PART;
    _Float16* g2   = (_Float16*)(ws + OFF_G2F);
    _Float16* sh   = (_Float16*)(ws + OFF_SH);
    float* s2g     = ws + OFF_S2G;
    float* cntf    = ws + OFF_CNT;                // 128 x 64B-padded counters

    prep_kernel<<<PREP_BLOCKS, 256, 0, stream>>>(grd, sat, g2, sh, s2g, inv, partial, dots, cntf);
    corr_mfma_kernel<<<dim3(M_SAT, 5, 8), 256, 0, stream>>>(sh, g2, partial);
    epilogue_kernel<<<M_SAT * N_GRD, 256, 0, stream>>>(partial, s2g, S, inv, unc, candv, candi);
    refine_dot_kernel<<<dim3(128, 4, 8), 256, 0, stream>>>(grd, sat, candv, candi, dots,
                                                           S, inv, unc, (unsigned*)cntf, out);
}

// Round 9
// 339.075 us; speedup vs baseline: 1.2642x; 1.2604x over previous
//
#include <hip/hip_runtime.h>
#include <math.h>

#define N_GRD 4
#define M_SAT 32
#define C_CH  32
#define HK    64
#define WK    64
#define HO    65
#define WO    65
#define SAMPLE_ELEMS (C_CH * HK * WK)

typedef _Float16 h8 __attribute__((ext_vector_type(8)));
typedef float    f4 __attribute__((ext_vector_type(4)));
typedef unsigned int u32;

// ---- ws layout (float units) ----
#define OFF_INV    0                  // inv[0..35]
#define OFF_S      64                 // 32 * 4225
#define OFF_CANDV  135264
#define OFF_CANDI  135776
#define OFF_DOTS   136288             // 512
#define OFF_PART   136800             // 32 m * 4 n * 80 xsl * 80 y = 819200
#define OFF_G2F    956000             // G2_HALFS/2 floats
#define OFF_SH     1824352            // 524288 granules * 8 halfs = 2097152 floats
#define OFF_S2G    3921504            // 32 m * 4096 raw squared-norm sums
#define G2_HALFS   1736704            // 2cp * 8cq * 64i * 4n * 106js * 4c

#define G2V_BLOCKS 848                // G2_HALFS/8 granules / 256
#define SH_BLOCKS  2048               // 524288/256
#define S2P_BLOCKS 256                // 32 m x 8 slices of 512 px (exact s2)
#define ZERO_BLOCKS 801               // partial 204800 f4 + dots 128 f4
#define PREP_BLOCKS (G2V_BLOCKS + SH_BLOCKS + S2P_BLOCKS + N_GRD + ZERO_BLOCKS)

// ---------------------------------------------------------------------------
// K1 (fused prep), by blockIdx range:
//  [0,848)         g2 Toeplitz build, vectorized (1 thread = 1 granule)
//  [848,2896)      sh build: fp16 sat in DMA-granule layout (16B stores)
//  [2896,3152)     s2g: per-pixel sum over 32 channels of sat^2, EXACT serial
//                  ascending-c order (bit-identical to original SAT phase 1),
//                  spread 32m x 8 slices -> no per-CU straggler.
//  [3152,3156)     grd inv-norms
//  [3156,3957)     zero partial + dots
// ---------------------------------------------------------------------------
__global__ __launch_bounds__(256) void prep_kernel(const float* __restrict__ grd,
                                                   const float* __restrict__ sat,
                                                   _Float16* __restrict__ g2,
                                                   _Float16* __restrict__ sh,
                                                   float* __restrict__ s2g,
                                                   float* __restrict__ inv,
                                                   float* __restrict__ partial,
                                                   float* __restrict__ dots) {
    const int bx = blockIdx.x;
    const int tid = threadIdx.x;

    if (bx < G2V_BLOCKS) {
        int g = bx * 256 + tid;            // granule index < 217088
        int t0 = g * 2;
        int js0 = t0 % 106;
        int r = t0 / 106;
        int n  = r & 3;
        int i  = (r >> 2) & 63;
        int cq = (r >> 8) & 7;
        int cp = r >> 11;
        int j0 = js0 - 16 - cp;            // halfs e<4 use j0, e>=4 use j0+1
        const float* gb = grd + (((size_t)n * 32 + cq * 4) * 64 + i) * 64;
        h8 hv;
#pragma unroll
        for (int c = 0; c < 4; ++c) {
            float v0 = (j0 >= 0 && j0 < 64) ? gb[c * 4096 + j0] : 0.0f;
            float v1 = (j0 + 1 >= 0 && j0 + 1 < 64) ? gb[c * 4096 + j0 + 1] : 0.0f;
            hv[c]     = (_Float16)v0;
            hv[c + 4] = (_Float16)v1;
        }
        *(h8*)(g2 + (size_t)g * 8) = hv;
        return;
    }
    if (bx < G2V_BLOCKS + SH_BLOCKS) {
        int idx = (bx - G2V_BLOCKS) * 256 + tid;   // granule index < 524288
        int gr = idx & 31;
        int r  = (idx >> 5) & 63;
        int cq = (idx >> 11) & 7;
        int mm = idx >> 14;
        const float* sp = sat + (((size_t)mm * 32 + cq * 4) * 64 + r) * 64 + gr * 2;
        float2 v0 = *(const float2*)(sp);
        float2 v1 = *(const float2*)(sp + 4096);
        float2 v2 = *(const float2*)(sp + 8192);
        float2 v3 = *(const float2*)(sp + 12288);
        h8 hv = {(_Float16)v0.x, (_Float16)v1.x, (_Float16)v2.x, (_Float16)v3.x,
                 (_Float16)v0.y, (_Float16)v1.y, (_Float16)v2.y, (_Float16)v3.y};
        *(h8*)(sh + (size_t)idx * 8) = hv;
        return;
    }
    if (bx < G2V_BLOCKS + SH_BLOCKS + S2P_BLOCKS) {
        int blk = bx - G2V_BLOCKS - SH_BLOCKS;
        int m = blk >> 3, sl = blk & 7;
        int px0 = sl * 512 + tid * 2;              // 2 adjacent pixels/thread
        const float* base = sat + (size_t)m * SAMPLE_ELEMS + px0;
        float sA = 0.0f, sB = 0.0f;
        for (int c = 0; c < C_CH; ++c) {           // exact ascending-c order
            float2 v = *(const float2*)(base + c * 4096);
            sA += v.x * v.x;
            sB += v.y * v.y;
        }
        s2g[(size_t)m * 4096 + px0]     = sA;
        s2g[(size_t)m * 4096 + px0 + 1] = sB;
        return;
    }
    if (bx < G2V_BLOCKS + SH_BLOCKS + S2P_BLOCKS + N_GRD) {
        // grd norms
        const int b = bx - G2V_BLOCKS - SH_BLOCKS - S2P_BLOCKS;
        const float4* v = reinterpret_cast<const float4*>(grd + (size_t)b * SAMPLE_ELEMS);
        float ss = 0.0f;
        for (int p = tid; p < SAMPLE_ELEMS / 4; p += 256) {
            float4 q = v[p];
            ss += q.x * q.x + q.y * q.y + q.z * q.z + q.w * q.w;
        }
        for (int off = 32; off > 0; off >>= 1) ss += __shfl_down(ss, off);
        __shared__ float ls[4];
        int lane = tid & 63, w = tid >> 6;
        if (lane == 0) ls[w] = ss;
        __syncthreads();
        if (tid == 0)
            inv[b] = 1.0f / fmaxf(sqrtf(ls[0] + ls[1] + ls[2] + ls[3]), 1e-12f);
        return;
    }
    {   // zero partial + dots (float4)
        int idx = (bx - G2V_BLOCKS - SH_BLOCKS - S2P_BLOCKS - N_GRD) * 256 + tid;
        f4 z = {0.f, 0.f, 0.f, 0.f};
        if (idx < 204800)                 *(f4*)(partial + (size_t)idx * 4) = z;
        else if (idx - 204800 < 128)      *(f4*)(dots + (size_t)(idx - 204800) * 4) = z;
    }
}

// ---------------------------------------------------------------------------
// K2: MFMA correlation (round-3 structure, best measured; UNCHANGED).
// Grid (m=32, xs=5, z=8: h=z&1, qt=z>>1); 4 waves = i.
// A staged per cqi via global_load_lds(16) from sh (zero-redirect padding),
// guarded by __syncthreads (2x per kernel).
// B is WAVE-PRIVATE: wave w only reads slices wi==w, so B staging needs no
// barrier.  Each wave stages its own 240 granules, double-buffered:
//    stage B(ii+1) -> s_waitcnt vmcnt(4) -> compute(ii)      [T3/T4]
// LDS = 48384 A + 2*15360 B = 79104 -> 2 blocks/CU.
// Output: fp32 atomicAdd into partial[m][n][xsl80][y80] (zeroed in prep).
// ---------------------------------------------------------------------------
__global__ __launch_bounds__(256, 2) void corr_mfma_kernel(const _Float16* __restrict__ sh,
                                                           const _Float16* __restrict__ g2,
                                                           float* __restrict__ partial) {
    __shared__ __align__(16) char lds[79104];
    char* AB = lds;                 // 48384
    char* BB = lds + 48384;         // 2 x 15360: [bsel][w4][cp2][n4][g30]x16B

    const int m  = blockIdx.x;
    const int xs = blockIdx.y;
    const int z  = blockIdx.z;
    const int h  = z & 1;
    const int qt = z >> 1;

    const int x00 = (xs < 4) ? 16 * xs : 49;
    const int qb  = (xs < 4) ? 16 * xs : 48;
    const int xoff = x00 - qb;
    const int qstage = qb + 40 * h;

    const int tid  = threadIdx.x;
    const int w    = tid >> 6;
    const int lane = tid & 63;
    const int s    = lane & 15;
    const int u    = lane >> 4;
    const int cp   = (s + xoff) & 1;

    f4 acc[5][4];
#pragma unroll
    for (int t = 0; t < 5; ++t)
#pragma unroll
        for (int n = 0; n < 4; ++n) { acc[t][n][0]=0.f; acc[t][n][1]=0.f; acc[t][n][2]=0.f; acc[t][n][3]=0.f; }

    const int woff = (16 - xoff + cp + 2 * u - s) * 8;
    const char* Blane = BB + w * 3840 + cp * 1920 + woff;
    const int abase0 = s * 336 + u * 16;
    const int q2base = qstage >> 1;

    size_t bsrc[4];
    bool bs_on[4];
#pragma unroll
    for (int k = 0; k < 4; ++k) {
        int idx = k * 64 + lane;
        bs_on[k] = idx < 240;
        int cpp = idx / 120; int rm = idx - cpp * 120;
        int nn = rm / 30;    int gg = rm - nn * 30;
        bsrc[k] = (size_t)cpp * 868352 + (size_t)nn * 424
                + (size_t)(gg + 20 * h) * 8 + (size_t)w * 27136;
    }

    auto stageA = [&](int cq) {
        for (int k = 0; k < 11; ++k) {
            int idx = k * 256 + tid;
            if (idx < 2688) {
                u32 r = (u32)idx / 21u;
                u32 g = (u32)idx - r * 21u;
                int q2 = q2base + (int)g;
                bool valid = (g < 20u) & (r >= 32u) & (r < 96u) & (q2 >= 16) & (q2 < 48);
                const _Float16* src = valid
                    ? sh + ((((size_t)m * 8 + cq) * 64 + (r - 32)) * 32 + (q2 - 16)) * 8
                    : g2;   // first granules of g2 are structurally zero
                __builtin_amdgcn_global_load_lds(
                    (const __attribute__((address_space(1))) u32*)(const void*)src,
                    (__attribute__((address_space(3))) u32*)(void*)(AB + k * 4096 + w * 1024),
                    16, 0, 0);
            }
        }
    };

    auto stageB = [&](int cq, int ii, int bsel) {
        asm volatile("s_waitcnt lgkmcnt(0)" ::: "memory");
        char* dst0 = BB + bsel * 15360 + w * 3840;
        const size_t add = (size_t)cq * 108544 + (size_t)ii * 1696;
#pragma unroll
        for (int k = 0; k < 4; ++k) {
            if (bs_on[k])
                __builtin_amdgcn_global_load_lds(
                    (const __attribute__((address_space(1))) u32*)(const void*)(g2 + bsrc[k] + add),
                    (__attribute__((address_space(3))) u32*)(void*)(dst0 + k * 1024),
                    16, 0, 0);
        }
    };

    auto compute = [&](int ii, int bsel) {
        const char* Ab = AB + abase0 + (w * 16 + ii) * 336;
        const char* Bb = Blane + bsel * 15360;
#pragma unroll
        for (int qs = 0; qs < 5; ++qs) {
            h8 a[5]; h8 bfr[4];
#pragma unroll
            for (int n = 0; n < 4; ++n) bfr[n] = *(const h8*)(Bb + qs * 64 + n * 480);
#pragma unroll
            for (int t = 0; t < 5; ++t) a[t] = *(const h8*)(Ab + qs * 64 + t * 5376);
#pragma unroll
            for (int t = 0; t < 5; ++t)
#pragma unroll
                for (int n = 0; n < 4; ++n)
                    acc[t][n] = __builtin_amdgcn_mfma_f32_16x16x32_f16(a[t], bfr[n], acc[t][n], 0, 0, 0);
        }
    };

    for (int cqi = 0; cqi < 2; ++cqi) {
        const int cq = qt * 2 + cqi;
        __syncthreads();          // prior readers of AB/BB done
        stageA(cq);
        stageB(cq, 0, 0);
        __syncthreads();          // full drain: A + B(0) resident
#pragma unroll 1
        for (int iip = 0; iip < 8; ++iip) {
            const int ii0 = 2 * iip;
            stageB(cq, ii0 + 1, 1);
            asm volatile("s_waitcnt vmcnt(4)" ::: "memory");
            compute(ii0, 0);
            if (iip < 7) {
                stageB(cq, ii0 + 2, 0);
                asm volatile("s_waitcnt vmcnt(4)" ::: "memory");
            } else {
                asm volatile("s_waitcnt vmcnt(0)" ::: "memory");
            }
            compute(ii0 + 1, 1);
        }
    }

    // ---- cross-wave (i) reduce in LDS, then atomicAdd into partial
    float* red = (float*)lds;
#pragma unroll
    for (int t = 0; t < 5; ++t) {
        __syncthreads();
#pragma unroll
        for (int nn = 0; nn < 4; ++nn)
            *(f4*)(red + ((nn * 4 + w) * 64 + lane) * 4) = acc[t][nn];
        __syncthreads();
        {
            int nn = tid >> 6, ln = tid & 63;
            f4 sum = *(f4*)(red + ((nn * 4 + 0) * 64 + ln) * 4);
            sum = sum + *(f4*)(red + ((nn * 4 + 1) * 64 + ln) * 4);
            sum = sum + *(f4*)(red + ((nn * 4 + 2) * 64 + ln) * 4);
            sum = sum + *(f4*)(red + ((nn * 4 + 3) * 64 + ln) * 4);
            int ss = ln & 15, uu = ln >> 4;
            float* dst = partial + ((size_t)(m * 4 + nn)) * 6400
                         + (xs * 16 + ss) * 80 + t * 16 + uu * 4;
#pragma unroll
            for (int l = 0; l < 4; ++l) atomicAdd(dst + l, sum[l]);
        }
    }
}

// ---------------------------------------------------------------------------
// K3: epilogue.  Builds the per-m prefix SAT in LDS from s2g (scan order
// bit-identical to the original), computes inv_sat locally; n==0 block
// persists S[m] + inv[4+m] for the refine kernels (later launches).
// Then normalize + top-4 candidates per (m,n).
// ---------------------------------------------------------------------------
__global__ __launch_bounds__(256) void epilogue_kernel(const float* __restrict__ partial,
                                                       const float* __restrict__ s2g,
                                                       float* __restrict__ S,
                                                       float* __restrict__ inv,
                                                       const int* __restrict__ unc,
                                                       float* __restrict__ candv,
                                                       int* __restrict__ candi) {
    const int b = blockIdx.x;
    const int m = b >> 2, n = b & 3;
    const int tid = threadIdx.x;
    __shared__ float P[64][65];

    // build prefix SAT (exact replica of original scans)
    const float* sg = s2g + (size_t)m * 4096;
    for (int idx = tid; idx < 4096; idx += 256) P[idx >> 6][idx & 63] = sg[idx];
    __syncthreads();
    if (tid < 64) {
        int r = tid; float run = 0.0f;
        for (int w = 0; w < 64; ++w) { run += P[r][w]; P[r][w] = run; }
    }
    __syncthreads();
    if (tid < 64) {
        int c = tid; float run = 0.0f;
        for (int h = 0; h < 64; ++h) { run += P[h][c]; P[h][c] = run; }
    }
    __syncthreads();
    const float isn = 1.0f / fmaxf(sqrtf(P[63][63]), 1e-12f);
    if (n == 0) {
        if (tid == 0) inv[N_GRD + m] = isn;
        float* Sm = S + (size_t)m * (HO * WO);
        for (int p = tid; p < HO * WO; p += 256) {
            int r = p / 65, c = p - r * 65;
            Sm[p] = (r == 0 || c == 0) ? 0.0f : P[r - 1][c - 1];
        }
    }

    const float uu = (float)unc[0];
    const float sc = inv[n] * isn;
    const float* pb = partial + (size_t)(m * 4 + n) * 6400;

    float best = -3.4e38f;
    int bidx = 0x7fffffff;
    for (int pp = tid; pp < 4225; pp += 256) {
        int x = pp / 65, y = pp - x * 65;
        int xsl = (x == 64) ? 79 : x;
        float raw = pb[xsl * 80 + y];
        float num = raw * sc;
        int r0 = max(0, y - 32), r1 = min(64, y + 32);
        int q0 = max(0, x - 32), q1 = min(64, x + 32);
        float s11 = P[r1 - 1][q1 - 1];
        float s01 = (r0 == 0) ? 0.0f : P[r0 - 1][q1 - 1];
        float s10 = (q0 == 0) ? 0.0f : P[r1 - 1][q0 - 1];
        float s00 = (r0 == 0 || q0 == 0) ? 0.0f : P[r0 - 1][q0 - 1];
        float ps = s11 - s01 - s10 + s00;
        float denom = fmaxf(sqrtf(ps) * isn * uu, 1e-12f);
        float v = num / denom;
        int p = y * 65 + x;
        if (v > best || (v == best && p < bidx)) { best = v; bidx = p; }
    }
    __shared__ float bv[256]; __shared__ int bi[256];
    __shared__ float cv[256]; __shared__ int ci[256];
    __shared__ int winner;
    bv[tid] = best; bi[tid] = bidx;
    __syncthreads();
    for (int round = 0; round < 4; ++round) {
        cv[tid] = bv[tid]; ci[tid] = bi[tid];
        __syncthreads();
        for (int st = 128; st > 0; st >>= 1) {
            if (tid < st) {
                float ov = cv[tid + st]; int oi = ci[tid + st];
                if (ov > cv[tid] || (ov == cv[tid] && oi < ci[tid])) { cv[tid] = ov; ci[tid] = oi; }
            }
            __syncthreads();
        }
        if (tid == 0) { candv[b * 4 + round] = cv[0]; candi[b * 4 + round] = ci[0]; winner = ci[0]; }
        __syncthreads();
        if (bi[tid] == winner) bv[tid] = -3.4e38f;
        __syncthreads();
    }
}

// ---------------------------------------------------------------------------
// K4a: exact fp32 dot for candidate (b,k), split over 8 c-chunks (grid z).
// atomicAdd partial dots (dots zeroed in prep).  No fences, early return.
// ---------------------------------------------------------------------------
__global__ __launch_bounds__(256) void refine_dot_kernel(const float* __restrict__ grd,
                                                         const float* __restrict__ sat,
                                                         const float* __restrict__ candv,
                                                         const int* __restrict__ candi,
                                                         float* __restrict__ dots) {
    const int b = blockIdx.x;
    const int k = blockIdx.y;
    const int cq = blockIdx.z;
    const int m = b >> 2, n = b & 3;
    float v0 = candv[b * 4];
    float thr = v0 - (0.02f * fabsf(v0) + 1e-4f);
    if (k > 0 && candv[b * 4 + k] < thr) return;   // dots stays 0 (zeroed)
    int p = candi[b * 4 + k];
    int y = p / 65, x = p - y * 65;
    const int tid = threadIdx.x, lane = tid & 63, w = tid >> 6;
    const int ilo = max(0, 32 - y), ihi = min(64, 96 - y);
    int xj = x + lane - 32;
    float acc = 0.0f;
    if (xj >= 0 && xj < 64) {
        const float* sm = sat + (size_t)m * SAMPLE_ELEMS;
        const float* gn = grd + (size_t)n * SAMPLE_ELEMS;
        for (int cc = 0; cc < 4; ++cc) {
            const int cbase = (cq * 4 + cc) << 12;
            const float* sp = sm + cbase + xj + ((y - 32) << 6);
            const float* gp = gn + cbase + lane;
            for (int i = ilo + w; i < ihi; i += 4)
                acc = fmaf(sp[i << 6], gp[i << 6], acc);
        }
    }
    for (int off = 32; off > 0; off >>= 1) acc += __shfl_down(acc, off);
    __shared__ float ls[4];
    if (lane == 0) ls[w] = acc;
    __syncthreads();
    if (tid == 0) atomicAdd(&dots[b * 4 + k], ls[0] + ls[1] + ls[2] + ls[3]);
}

// ---------------------------------------------------------------------------
// K4b: pick best refined candidate per (m,n), write outputs.  1 block.
// ---------------------------------------------------------------------------
__global__ __launch_bounds__(128) void refine_pick_kernel(const float* __restrict__ S,
                                                          const float* __restrict__ inv,
                                                          const int* __restrict__ unc,
                                                          const float* __restrict__ candv,
                                                          const int* __restrict__ candi,
                                                          const float* __restrict__ dots,
                                                          float* __restrict__ out) {
    int b = threadIdx.x;
    if (b >= 128) return;
    const int m = b >> 2, n = b & 3;
    const float uu = (float)unc[0];
    const float sc = inv[n] * inv[N_GRD + m];
    const float isn = inv[N_GRD + m];
    const float* Sm = S + (size_t)m * 4225;
    float v0 = candv[b * 4];
    float thr = v0 - (0.02f * fabsf(v0) + 1e-4f);
    float bestv = -3.4e38f; int bestp = 0x7fffffff;
    for (int k = 0; k < 4; ++k) {
        if (k > 0 && candv[b * 4 + k] < thr) break;   // candv sorted desc
        int p = candi[b * 4 + k];
        int y = p / 65, x = p - y * 65;
        int r0 = max(0, y - 32), r1 = min(64, y + 32);
        int q0 = max(0, x - 32), q1 = min(64, x + 32);
        float ps = Sm[r1 * 65 + q1] - Sm[r0 * 65 + q1] - Sm[r1 * 65 + q0] + Sm[r0 * 65 + q0];
        float denom = fmaxf(sqrtf(ps) * isn * uu, 1e-12f);
        float v = dots[b * 4 + k] * sc / denom;
        if (v > bestv || (v == bestv && p < bestp)) { bestv = v; bestp = p; }
    }
    out[b] = bestv;
    int row = bestp / 65, col = bestp - row * 65;
    float pr = -((float)row - 32.5f);
    float pc = (float)col - 32.5f;
    out[128 + b * 2 + 0] = ((pr * 0.2f) * 512.0f) * (1.0f / 128.0f);
    out[128 + b * 2 + 1] = ((pc * 0.2f) * 512.0f) * (1.0f / 128.0f);
}

// ---------------------------------------------------------------------------
extern "C" void kernel_launch(void* const* d_in, const int* in_sizes, int n_in,
                              void* d_out, int out_size, void* d_ws, size_t ws_size,
                              hipStream_t stream) {
    const float* grd = (const float*)d_in[0];
    const float* sat = (const float*)d_in[1];
    const int*   unc = (const int*)d_in[2];
    float* out = (float*)d_out;
    float* ws  = (float*)d_ws;

    float* inv     = ws + OFF_INV;
    float* S       = ws + OFF_S;
    float* candv   = ws + OFF_CANDV;
    int*   candi   = (int*)(ws + OFF_CANDI);
    float* dots    = ws + OFF_DOTS;
    float* partial = ws + OFF_PART;
    _Float16* g2   = (_Float16*)(ws + OFF_G2F);
    _Float16* sh   = (_Float16*)(ws + OFF_SH);
    float* s2g     = ws + OFF_S2G;                // ~16.2 MB total ws use

    prep_kernel<<<PREP_BLOCKS, 256, 0, stream>>>(grd, sat, g2, sh, s2g, inv, partial, dots);
    corr_mfma_kernel<<<dim3(M_SAT, 5, 8), 256, 0, stream>>>(sh, g2, partial);
    epilogue_kernel<<<M_SAT * N_GRD, 256, 0, stream>>>(partial, s2g, S, inv, unc, candv, candi);
    refine_dot_kernel<<<dim3(128, 4, 8), 256, 0, stream>>>(grd, sat, candv, candi, dots);
    refine_pick_kernel<<<1, 128, 0, stream>>>(S, inv, unc, candv, candi, dots, out);
}

// Round 10
// 338.133 us; speedup vs baseline: 1.2677x; 1.0028x over previous
//
#include <hip/hip_runtime.h>
#include <math.h>

#define N_GRD 4
#define M_SAT 32
#define C_CH  32
#define HK    64
#define WK    64
#define HO    65
#define WO    65
#define SAMPLE_ELEMS (C_CH * HK * WK)

typedef _Float16 h8 __attribute__((ext_vector_type(8)));
typedef float    f4 __attribute__((ext_vector_type(4)));
typedef unsigned int u32;

// ---- ws layout (float units) ----
#define OFF_INV    0                  // inv[0..35]
#define OFF_S      64                 // 32 * 4225
#define OFF_CANDV  135264
#define OFF_CANDI  135776
#define OFF_DOTS   136288             // 512
#define OFF_PART   136800             // 32 m * 4 n * 80 xsl * 80 y = 819200
#define OFF_G2F    956000             // G2_HALFS/2 floats
#define OFF_SH     1824352            // 524288 granules * 8 halfs = 2097152 floats
#define OFF_S2G    3921504            // 32 m * 4096 raw squared-norm sums
#define G2_HALFS   1736704            // 2cp * 8cq * 64i * 4n * 106js * 4c

#define G2V_BLOCKS 848                // G2_HALFS/8 granules / 256
#define SH_BLOCKS  2048               // 524288/256
#define S2P_BLOCKS 256                // 32 m x 8 slices of 512 px (exact s2)
#define ZERO_BLOCKS 801               // partial 204800 f4 + dots 128 f4
#define PREP_BLOCKS (G2V_BLOCKS + SH_BLOCKS + S2P_BLOCKS + N_GRD + ZERO_BLOCKS)

// ---------------------------------------------------------------------------
// K1 (fused prep), by blockIdx range:
//  [0,848)         g2 Toeplitz build, vectorized (1 thread = 1 granule)
//  [848,2896)      sh build: fp16 sat in DMA-granule layout (16B stores)
//  [2896,3152)     s2g: per-pixel sum over 32 channels of sat^2, EXACT serial
//                  ascending-c order (bit-identical to original SAT phase 1),
//                  spread 32m x 8 slices -> no per-CU straggler.
//  [3152,3156)     grd inv-norms
//  [3156,3957)     zero partial + dots
// ---------------------------------------------------------------------------
__global__ __launch_bounds__(256) void prep_kernel(const float* __restrict__ grd,
                                                   const float* __restrict__ sat,
                                                   _Float16* __restrict__ g2,
                                                   _Float16* __restrict__ sh,
                                                   float* __restrict__ s2g,
                                                   float* __restrict__ inv,
                                                   float* __restrict__ partial,
                                                   float* __restrict__ dots) {
    const int bx = blockIdx.x;
    const int tid = threadIdx.x;

    if (bx < G2V_BLOCKS) {
        int g = bx * 256 + tid;            // granule index < 217088
        int t0 = g * 2;
        int js0 = t0 % 106;
        int r = t0 / 106;
        int n  = r & 3;
        int i  = (r >> 2) & 63;
        int cq = (r >> 8) & 7;
        int cp = r >> 11;
        int j0 = js0 - 16 - cp;            // halfs e<4 use j0, e>=4 use j0+1
        const float* gb = grd + (((size_t)n * 32 + cq * 4) * 64 + i) * 64;
        h8 hv;
#pragma unroll
        for (int c = 0; c < 4; ++c) {
            float v0 = (j0 >= 0 && j0 < 64) ? gb[c * 4096 + j0] : 0.0f;
            float v1 = (j0 + 1 >= 0 && j0 + 1 < 64) ? gb[c * 4096 + j0 + 1] : 0.0f;
            hv[c]     = (_Float16)v0;
            hv[c + 4] = (_Float16)v1;
        }
        *(h8*)(g2 + (size_t)g * 8) = hv;
        return;
    }
    if (bx < G2V_BLOCKS + SH_BLOCKS) {
        int idx = (bx - G2V_BLOCKS) * 256 + tid;   // granule index < 524288
        int gr = idx & 31;
        int r  = (idx >> 5) & 63;
        int cq = (idx >> 11) & 7;
        int mm = idx >> 14;
        const float* sp = sat + (((size_t)mm * 32 + cq * 4) * 64 + r) * 64 + gr * 2;
        float2 v0 = *(const float2*)(sp);
        float2 v1 = *(const float2*)(sp + 4096);
        float2 v2 = *(const float2*)(sp + 8192);
        float2 v3 = *(const float2*)(sp + 12288);
        h8 hv = {(_Float16)v0.x, (_Float16)v1.x, (_Float16)v2.x, (_Float16)v3.x,
                 (_Float16)v0.y, (_Float16)v1.y, (_Float16)v2.y, (_Float16)v3.y};
        *(h8*)(sh + (size_t)idx * 8) = hv;
        return;
    }
    if (bx < G2V_BLOCKS + SH_BLOCKS + S2P_BLOCKS) {
        int blk = bx - G2V_BLOCKS - SH_BLOCKS;
        int m = blk >> 3, sl = blk & 7;
        int px0 = sl * 512 + tid * 2;              // 2 adjacent pixels/thread
        const float* base = sat + (size_t)m * SAMPLE_ELEMS + px0;
        float sA = 0.0f, sB = 0.0f;
        for (int c = 0; c < C_CH; ++c) {           // exact ascending-c order
            float2 v = *(const float2*)(base + c * 4096);
            sA += v.x * v.x;
            sB += v.y * v.y;
        }
        s2g[(size_t)m * 4096 + px0]     = sA;
        s2g[(size_t)m * 4096 + px0 + 1] = sB;
        return;
    }
    if (bx < G2V_BLOCKS + SH_BLOCKS + S2P_BLOCKS + N_GRD) {
        // grd norms
        const int b = bx - G2V_BLOCKS - SH_BLOCKS - S2P_BLOCKS;
        const float4* v = reinterpret_cast<const float4*>(grd + (size_t)b * SAMPLE_ELEMS);
        float ss = 0.0f;
        for (int p = tid; p < SAMPLE_ELEMS / 4; p += 256) {
            float4 q = v[p];
            ss += q.x * q.x + q.y * q.y + q.z * q.z + q.w * q.w;
        }
        for (int off = 32; off > 0; off >>= 1) ss += __shfl_down(ss, off);
        __shared__ float ls[4];
        int lane = tid & 63, w = tid >> 6;
        if (lane == 0) ls[w] = ss;
        __syncthreads();
        if (tid == 0)
            inv[b] = 1.0f / fmaxf(sqrtf(ls[0] + ls[1] + ls[2] + ls[3]), 1e-12f);
        return;
    }
    {   // zero partial + dots (float4)
        int idx = (bx - G2V_BLOCKS - SH_BLOCKS - S2P_BLOCKS - N_GRD) * 256 + tid;
        f4 z = {0.f, 0.f, 0.f, 0.f};
        if (idx < 204800)                 *(f4*)(partial + (size_t)idx * 4) = z;
        else if (idx - 204800 < 128)      *(f4*)(dots + (size_t)(idx - 204800) * 4) = z;
    }
}

// ---------------------------------------------------------------------------
// K2: MFMA correlation (round-3 structure) + T5 s_setprio around the MFMA
// cluster.  Grid (m=32, xs=5, z=8: h=z&1, qt=z>>1); 4 waves = i.
// A staged per cqi via global_load_lds(16) from sh (zero-redirect padding),
// guarded by __syncthreads (2x per kernel).
// B is WAVE-PRIVATE double-buffered, no barriers in the ii loop:
//    stage B(ii+1) -> s_waitcnt vmcnt(4) -> compute(ii)      [T3/T4]
// Waves drift to different phases (stage vs compute) -> setprio(1) during
// the MFMA cluster lets compute-phase waves win issue arbitration [T5].
// LDS = 48384 A + 2*15360 B = 79104 -> 2 blocks/CU.
// Output: fp32 atomicAdd into partial[m][n][xsl80][y80] (zeroed in prep).
// ---------------------------------------------------------------------------
__global__ __launch_bounds__(256, 2) void corr_mfma_kernel(const _Float16* __restrict__ sh,
                                                           const _Float16* __restrict__ g2,
                                                           float* __restrict__ partial) {
    __shared__ __align__(16) char lds[79104];
    char* AB = lds;                 // 48384
    char* BB = lds + 48384;         // 2 x 15360: [bsel][w4][cp2][n4][g30]x16B

    const int m  = blockIdx.x;
    const int xs = blockIdx.y;
    const int z  = blockIdx.z;
    const int h  = z & 1;
    const int qt = z >> 1;

    const int x00 = (xs < 4) ? 16 * xs : 49;
    const int qb  = (xs < 4) ? 16 * xs : 48;
    const int xoff = x00 - qb;
    const int qstage = qb + 40 * h;

    const int tid  = threadIdx.x;
    const int w    = tid >> 6;
    const int lane = tid & 63;
    const int s    = lane & 15;
    const int u    = lane >> 4;
    const int cp   = (s + xoff) & 1;

    f4 acc[5][4];
#pragma unroll
    for (int t = 0; t < 5; ++t)
#pragma unroll
        for (int n = 0; n < 4; ++n) { acc[t][n][0]=0.f; acc[t][n][1]=0.f; acc[t][n][2]=0.f; acc[t][n][3]=0.f; }

    const int woff = (16 - xoff + cp + 2 * u - s) * 8;
    const char* Blane = BB + w * 3840 + cp * 1920 + woff;
    const int abase0 = s * 336 + u * 16;
    const int q2base = qstage >> 1;

    size_t bsrc[4];
    bool bs_on[4];
#pragma unroll
    for (int k = 0; k < 4; ++k) {
        int idx = k * 64 + lane;
        bs_on[k] = idx < 240;
        int cpp = idx / 120; int rm = idx - cpp * 120;
        int nn = rm / 30;    int gg = rm - nn * 30;
        bsrc[k] = (size_t)cpp * 868352 + (size_t)nn * 424
                + (size_t)(gg + 20 * h) * 8 + (size_t)w * 27136;
    }

    auto stageA = [&](int cq) {
        for (int k = 0; k < 11; ++k) {
            int idx = k * 256 + tid;
            if (idx < 2688) {
                u32 r = (u32)idx / 21u;
                u32 g = (u32)idx - r * 21u;
                int q2 = q2base + (int)g;
                bool valid = (g < 20u) & (r >= 32u) & (r < 96u) & (q2 >= 16) & (q2 < 48);
                const _Float16* src = valid
                    ? sh + ((((size_t)m * 8 + cq) * 64 + (r - 32)) * 32 + (q2 - 16)) * 8
                    : g2;   // first granules of g2 are structurally zero
                __builtin_amdgcn_global_load_lds(
                    (const __attribute__((address_space(1))) u32*)(const void*)src,
                    (__attribute__((address_space(3))) u32*)(void*)(AB + k * 4096 + w * 1024),
                    16, 0, 0);
            }
        }
    };

    auto stageB = [&](int cq, int ii, int bsel) {
        asm volatile("s_waitcnt lgkmcnt(0)" ::: "memory");
        char* dst0 = BB + bsel * 15360 + w * 3840;
        const size_t add = (size_t)cq * 108544 + (size_t)ii * 1696;
#pragma unroll
        for (int k = 0; k < 4; ++k) {
            if (bs_on[k])
                __builtin_amdgcn_global_load_lds(
                    (const __attribute__((address_space(1))) u32*)(const void*)(g2 + bsrc[k] + add),
                    (__attribute__((address_space(3))) u32*)(void*)(dst0 + k * 1024),
                    16, 0, 0);
        }
    };

    auto compute = [&](int ii, int bsel) {
        const char* Ab = AB + abase0 + (w * 16 + ii) * 336;
        const char* Bb = Blane + bsel * 15360;
#pragma unroll
        for (int qs = 0; qs < 5; ++qs) {
            h8 a[5]; h8 bfr[4];
#pragma unroll
            for (int n = 0; n < 4; ++n) bfr[n] = *(const h8*)(Bb + qs * 64 + n * 480);
#pragma unroll
            for (int t = 0; t < 5; ++t) a[t] = *(const h8*)(Ab + qs * 64 + t * 5376);
            __builtin_amdgcn_s_setprio(1);                 // T5: favor MFMA wave
#pragma unroll
            for (int t = 0; t < 5; ++t)
#pragma unroll
                for (int n = 0; n < 4; ++n)
                    acc[t][n] = __builtin_amdgcn_mfma_f32_16x16x32_f16(a[t], bfr[n], acc[t][n], 0, 0, 0);
            __builtin_amdgcn_s_setprio(0);
        }
    };

    for (int cqi = 0; cqi < 2; ++cqi) {
        const int cq = qt * 2 + cqi;
        __syncthreads();          // prior readers of AB/BB done
        stageA(cq);
        stageB(cq, 0, 0);
        __syncthreads();          // full drain: A + B(0) resident
#pragma unroll 1
        for (int iip = 0; iip < 8; ++iip) {
            const int ii0 = 2 * iip;
            stageB(cq, ii0 + 1, 1);
            asm volatile("s_waitcnt vmcnt(4)" ::: "memory");
            compute(ii0, 0);
            if (iip < 7) {
                stageB(cq, ii0 + 2, 0);
                asm volatile("s_waitcnt vmcnt(4)" ::: "memory");
            } else {
                asm volatile("s_waitcnt vmcnt(0)" ::: "memory");
            }
            compute(ii0 + 1, 1);
        }
    }

    // ---- cross-wave (i) reduce in LDS, then atomicAdd into partial
    float* red = (float*)lds;
#pragma unroll
    for (int t = 0; t < 5; ++t) {
        __syncthreads();
#pragma unroll
        for (int nn = 0; nn < 4; ++nn)
            *(f4*)(red + ((nn * 4 + w) * 64 + lane) * 4) = acc[t][nn];
        __syncthreads();
        {
            int nn = tid >> 6, ln = tid & 63;
            f4 sum = *(f4*)(red + ((nn * 4 + 0) * 64 + ln) * 4);
            sum = sum + *(f4*)(red + ((nn * 4 + 1) * 64 + ln) * 4);
            sum = sum + *(f4*)(red + ((nn * 4 + 2) * 64 + ln) * 4);
            sum = sum + *(f4*)(red + ((nn * 4 + 3) * 64 + ln) * 4);
            int ss = ln & 15, uu = ln >> 4;
            float* dst = partial + ((size_t)(m * 4 + nn)) * 6400
                         + (xs * 16 + ss) * 80 + t * 16 + uu * 4;
#pragma unroll
            for (int l = 0; l < 4; ++l) atomicAdd(dst + l, sum[l]);
        }
    }
}

// ---------------------------------------------------------------------------
// K3: epilogue.  Builds the per-m prefix SAT in LDS from s2g (scan order
// bit-identical to the original), computes inv_sat locally; n==0 block
// persists S[m] + inv[4+m] for the refine kernels (later launches).
// Then normalize + top-4 candidates per (m,n).
// ---------------------------------------------------------------------------
__global__ __launch_bounds__(256) void epilogue_kernel(const float* __restrict__ partial,
                                                       const float* __restrict__ s2g,
                                                       float* __restrict__ S,
                                                       float* __restrict__ inv,
                                                       const int* __restrict__ unc,
                                                       float* __restrict__ candv,
                                                       int* __restrict__ candi) {
    const int b = blockIdx.x;
    const int m = b >> 2, n = b & 3;
    const int tid = threadIdx.x;
    __shared__ float P[64][65];

    // build prefix SAT (exact replica of original scans)
    const float* sg = s2g + (size_t)m * 4096;
    for (int idx = tid; idx < 4096; idx += 256) P[idx >> 6][idx & 63] = sg[idx];
    __syncthreads();
    if (tid < 64) {
        int r = tid; float run = 0.0f;
        for (int w = 0; w < 64; ++w) { run += P[r][w]; P[r][w] = run; }
    }
    __syncthreads();
    if (tid < 64) {
        int c = tid; float run = 0.0f;
        for (int h = 0; h < 64; ++h) { run += P[h][c]; P[h][c] = run; }
    }
    __syncthreads();
    const float isn = 1.0f / fmaxf(sqrtf(P[63][63]), 1e-12f);
    if (n == 0) {
        if (tid == 0) inv[N_GRD + m] = isn;
        float* Sm = S + (size_t)m * (HO * WO);
        for (int p = tid; p < HO * WO; p += 256) {
            int r = p / 65, c = p - r * 65;
            Sm[p] = (r == 0 || c == 0) ? 0.0f : P[r - 1][c - 1];
        }
    }

    const float uu = (float)unc[0];
    const float sc = inv[n] * isn;
    const float* pb = partial + (size_t)(m * 4 + n) * 6400;

    float best = -3.4e38f;
    int bidx = 0x7fffffff;
    for (int pp = tid; pp < 4225; pp += 256) {
        int x = pp / 65, y = pp - x * 65;
        int xsl = (x == 64) ? 79 : x;
        float raw = pb[xsl * 80 + y];
        float num = raw * sc;
        int r0 = max(0, y - 32), r1 = min(64, y + 32);
        int q0 = max(0, x - 32), q1 = min(64, x + 32);
        float s11 = P[r1 - 1][q1 - 1];
        float s01 = (r0 == 0) ? 0.0f : P[r0 - 1][q1 - 1];
        float s10 = (q0 == 0) ? 0.0f : P[r1 - 1][q0 - 1];
        float s00 = (r0 == 0 || q0 == 0) ? 0.0f : P[r0 - 1][q0 - 1];
        float ps = s11 - s01 - s10 + s00;
        float denom = fmaxf(sqrtf(ps) * isn * uu, 1e-12f);
        float v = num / denom;
        int p = y * 65 + x;
        if (v > best || (v == best && p < bidx)) { best = v; bidx = p; }
    }
    __shared__ float bv[256]; __shared__ int bi[256];
    __shared__ float cv[256]; __shared__ int ci[256];
    __shared__ int winner;
    bv[tid] = best; bi[tid] = bidx;
    __syncthreads();
    for (int round = 0; round < 4; ++round) {
        cv[tid] = bv[tid]; ci[tid] = bi[tid];
        __syncthreads();
        for (int st = 128; st > 0; st >>= 1) {
            if (tid < st) {
                float ov = cv[tid + st]; int oi = ci[tid + st];
                if (ov > cv[tid] || (ov == cv[tid] && oi < ci[tid])) { cv[tid] = ov; ci[tid] = oi; }
            }
            __syncthreads();
        }
        if (tid == 0) { candv[b * 4 + round] = cv[0]; candi[b * 4 + round] = ci[0]; winner = ci[0]; }
        __syncthreads();
        if (bi[tid] == winner) bv[tid] = -3.4e38f;
        __syncthreads();
    }
}

// ---------------------------------------------------------------------------
// K4a: exact fp32 dot for candidate (b,k), split over 8 c-chunks (grid z).
// atomicAdd partial dots (dots zeroed in prep).  No fences, early return.
// ---------------------------------------------------------------------------
__global__ __launch_bounds__(256) void refine_dot_kernel(const float* __restrict__ grd,
                                                         const float* __restrict__ sat,
                                                         const float* __restrict__ candv,
                                                         const int* __restrict__ candi,
                                                         float* __restrict__ dots) {
    const int b = blockIdx.x;
    const int k = blockIdx.y;
    const int cq = blockIdx.z;
    const int m = b >> 2, n = b & 3;
    float v0 = candv[b * 4];
    float thr = v0 - (0.02f * fabsf(v0) + 1e-4f);
    if (k > 0 && candv[b * 4 + k] < thr) return;   // dots stays 0 (zeroed)
    int p = candi[b * 4 + k];
    int y = p / 65, x = p - y * 65;
    const int tid = threadIdx.x, lane = tid & 63, w = tid >> 6;
    const int ilo = max(0, 32 - y), ihi = min(64, 96 - y);
    int xj = x + lane - 32;
    float acc = 0.0f;
    if (xj >= 0 && xj < 64) {
        const float* sm = sat + (size_t)m * SAMPLE_ELEMS;
        const float* gn = grd + (size_t)n * SAMPLE_ELEMS;
        for (int cc = 0; cc < 4; ++cc) {
            const int cbase = (cq * 4 + cc) << 12;
            const float* sp = sm + cbase + xj + ((y - 32) << 6);
            const float* gp = gn + cbase + lane;
            for (int i = ilo + w; i < ihi; i += 4)
                acc = fmaf(sp[i << 6], gp[i << 6], acc);
        }
    }
    for (int off = 32; off > 0; off >>= 1) acc += __shfl_down(acc, off);
    __shared__ float ls[4];
    if (lane == 0) ls[w] = acc;
    __syncthreads();
    if (tid == 0) atomicAdd(&dots[b * 4 + k], ls[0] + ls[1] + ls[2] + ls[3]);
}

// ---------------------------------------------------------------------------
// K4b: pick best refined candidate per (m,n), write outputs.  1 block.
// ---------------------------------------------------------------------------
__global__ __launch_bounds__(128) void refine_pick_kernel(const float* __restrict__ S,
                                                          const float* __restrict__ inv,
                                                          const int* __restrict__ unc,
                                                          const float* __restrict__ candv,
                                                          const int* __restrict__ candi,
                                                          const float* __restrict__ dots,
                                                          float* __restrict__ out) {
    int b = threadIdx.x;
    if (b >= 128) return;
    const int m = b >> 2, n = b & 3;
    const float uu = (float)unc[0];
    const float sc = inv[n] * inv[N_GRD + m];
    const float isn = inv[N_GRD + m];
    const float* Sm = S + (size_t)m * 4225;
    float v0 = candv[b * 4];
    float thr = v0 - (0.02f * fabsf(v0) + 1e-4f);
    float bestv = -3.4e38f; int bestp = 0x7fffffff;
    for (int k = 0; k < 4; ++k) {
        if (k > 0 && candv[b * 4 + k] < thr) break;   // candv sorted desc
        int p = candi[b * 4 + k];
        int y = p / 65, x = p - y * 65;
        int r0 = max(0, y - 32), r1 = min(64, y + 32);
        int q0 = max(0, x - 32), q1 = min(64, x + 32);
        float ps = Sm[r1 * 65 + q1] - Sm[r0 * 65 + q1] - Sm[r1 * 65 + q0] + Sm[r0 * 65 + q0];
        float denom = fmaxf(sqrtf(ps) * isn * uu, 1e-12f);
        float v = dots[b * 4 + k] * sc / denom;
        if (v > bestv || (v == bestv && p < bestp)) { bestv = v; bestp = p; }
    }
    out[b] = bestv;
    int row = bestp / 65, col = bestp - row * 65;
    float pr = -((float)row - 32.5f);
    float pc = (float)col - 32.5f;
    out[128 + b * 2 + 0] = ((pr * 0.2f) * 512.0f) * (1.0f / 128.0f);
    out[128 + b * 2 + 1] = ((pc * 0.2f) * 512.0f) * (1.0f / 128.0f);
}

// ---------------------------------------------------------------------------
extern "C" void kernel_launch(void* const* d_in, const int* in_sizes, int n_in,
                              void* d_out, int out_size, void* d_ws, size_t ws_size,
                              hipStream_t stream) {
    const float* grd = (const float*)d_in[0];
    const float* sat = (const float*)d_in[1];
    const int*   unc = (const int*)d_in[2];
    float* out = (float*)d_out;
    float* ws  = (float*)d_ws;

    float* inv     = ws + OFF_INV;
    float* S       = ws + OFF_S;
    float* candv   = ws + OFF_CANDV;
    int*   candi   = (int*)(ws + OFF_CANDI);
    float* dots    = ws + OFF_DOTS;
    float* partial = ws + OFF_PART;
    _Float16* g2   = (_Float16*)(ws + OFF_G2F);
    _Float16* sh   = (_Float16*)(ws + OFF_SH);
    float* s2g     = ws + OFF_S2G;                // ~16.2 MB total ws use

    prep_kernel<<<PREP_BLOCKS, 256, 0, stream>>>(grd, sat, g2, sh, s2g, inv, partial, dots);
    corr_mfma_kernel<<<dim3(M_SAT, 5, 8), 256, 0, stream>>>(sh, g2, partial);
    epilogue_kernel<<<M_SAT * N_GRD, 256, 0, stream>>>(partial, s2g, S, inv, unc, candv, candi);
    refine_dot_kernel<<<dim3(128, 4, 8), 256, 0, stream>>>(grd, sat, candv, candi, dots);
    refine_pick_kernel<<<1, 128, 0, stream>>>(S, inv, unc, candv, candi, dots, out);
}

// Round 11
// 313.303 us; speedup vs baseline: 1.3682x; 1.0793x over previous
//
#include <hip/hip_runtime.h>
#include <math.h>

#define N_GRD 4
#define M_SAT 32
#define C_CH  32
#define HK    64
#define WK    64
#define HO    65
#define WO    65
#define SAMPLE_ELEMS (C_CH * HK * WK)

typedef _Float16 h8 __attribute__((ext_vector_type(8)));
typedef float    f4 __attribute__((ext_vector_type(4)));
typedef unsigned int u32;

// ---- ws layout (float units) ----
#define OFF_INV    0                  // inv[0..35]
#define OFF_S      64                 // 32 * 4225
#define OFF_CANDV  135264
#define OFF_CANDI  135776
#define OFF_DOTS   136288             // 512
#define OFF_PART   136800             // 32 m * 4 n * 80 xsl * 80 y = 819200
#define OFF_G2F    956000             // G2_HALFS/2 floats
#define OFF_SH     1824352            // 524288 granules * 8 halfs = 2097152 floats
#define OFF_S2G    3921504            // 32 m * 4096 raw squared-norm sums
#define OFF_SLAB   4052576            // optional: 8 z-slabs * 819200 floats
#define ZSTRIDE    819200
#define G2_HALFS   1736704            // 2cp * 8cq * 64i * 4n * 106js * 4c

#define G2V_BLOCKS 848                // G2_HALFS/8 granules / 256
#define SH_BLOCKS  2048               // 524288/256
#define S2P_BLOCKS 256                // 32 m x 8 slices of 512 px (exact s2)
#define ZERO_BLOCKS 801               // partial 204800 f4 + dots 128 f4
#define PREP_BLOCKS (G2V_BLOCKS + SH_BLOCKS + S2P_BLOCKS + N_GRD + ZERO_BLOCKS)

// ---------------------------------------------------------------------------
// K1 (fused prep), by blockIdx range:
//  [0,848)         g2 Toeplitz build, vectorized (1 thread = 1 granule)
//  [848,2896)      sh build: fp16 sat in DMA-granule layout (16B stores)
//  [2896,3152)     s2g: per-pixel sum over 32 channels of sat^2, EXACT serial
//                  ascending-c order (bit-identical to original SAT phase 1),
//                  spread 32m x 8 slices -> no per-CU straggler.
//  [3152,3156)     grd inv-norms
//  [3156,3957)     zero partial + dots (partial-zero only needed by the
//                  atomic fallback path; harmless in slab mode)
// ---------------------------------------------------------------------------
__global__ __launch_bounds__(256) void prep_kernel(const float* __restrict__ grd,
                                                   const float* __restrict__ sat,
                                                   _Float16* __restrict__ g2,
                                                   _Float16* __restrict__ sh,
                                                   float* __restrict__ s2g,
                                                   float* __restrict__ inv,
                                                   float* __restrict__ partial,
                                                   float* __restrict__ dots) {
    const int bx = blockIdx.x;
    const int tid = threadIdx.x;

    if (bx < G2V_BLOCKS) {
        int g = bx * 256 + tid;            // granule index < 217088
        int t0 = g * 2;
        int js0 = t0 % 106;
        int r = t0 / 106;
        int n  = r & 3;
        int i  = (r >> 2) & 63;
        int cq = (r >> 8) & 7;
        int cp = r >> 11;
        int j0 = js0 - 16 - cp;            // halfs e<4 use j0, e>=4 use j0+1
        const float* gb = grd + (((size_t)n * 32 + cq * 4) * 64 + i) * 64;
        h8 hv;
#pragma unroll
        for (int c = 0; c < 4; ++c) {
            float v0 = (j0 >= 0 && j0 < 64) ? gb[c * 4096 + j0] : 0.0f;
            float v1 = (j0 + 1 >= 0 && j0 + 1 < 64) ? gb[c * 4096 + j0 + 1] : 0.0f;
            hv[c]     = (_Float16)v0;
            hv[c + 4] = (_Float16)v1;
        }
        *(h8*)(g2 + (size_t)g * 8) = hv;
        return;
    }
    if (bx < G2V_BLOCKS + SH_BLOCKS) {
        int idx = (bx - G2V_BLOCKS) * 256 + tid;   // granule index < 524288
        int gr = idx & 31;
        int r  = (idx >> 5) & 63;
        int cq = (idx >> 11) & 7;
        int mm = idx >> 14;
        const float* sp = sat + (((size_t)mm * 32 + cq * 4) * 64 + r) * 64 + gr * 2;
        float2 v0 = *(const float2*)(sp);
        float2 v1 = *(const float2*)(sp + 4096);
        float2 v2 = *(const float2*)(sp + 8192);
        float2 v3 = *(const float2*)(sp + 12288);
        h8 hv = {(_Float16)v0.x, (_Float16)v1.x, (_Float16)v2.x, (_Float16)v3.x,
                 (_Float16)v0.y, (_Float16)v1.y, (_Float16)v2.y, (_Float16)v3.y};
        *(h8*)(sh + (size_t)idx * 8) = hv;
        return;
    }
    if (bx < G2V_BLOCKS + SH_BLOCKS + S2P_BLOCKS) {
        int blk = bx - G2V_BLOCKS - SH_BLOCKS;
        int m = blk >> 3, sl = blk & 7;
        int px0 = sl * 512 + tid * 2;              // 2 adjacent pixels/thread
        const float* base = sat + (size_t)m * SAMPLE_ELEMS + px0;
        float sA = 0.0f, sB = 0.0f;
        for (int c = 0; c < C_CH; ++c) {           // exact ascending-c order
            float2 v = *(const float2*)(base + c * 4096);
            sA += v.x * v.x;
            sB += v.y * v.y;
        }
        s2g[(size_t)m * 4096 + px0]     = sA;
        s2g[(size_t)m * 4096 + px0 + 1] = sB;
        return;
    }
    if (bx < G2V_BLOCKS + SH_BLOCKS + S2P_BLOCKS + N_GRD) {
        // grd norms
        const int b = bx - G2V_BLOCKS - SH_BLOCKS - S2P_BLOCKS;
        const float4* v = reinterpret_cast<const float4*>(grd + (size_t)b * SAMPLE_ELEMS);
        float ss = 0.0f;
        for (int p = tid; p < SAMPLE_ELEMS / 4; p += 256) {
            float4 q = v[p];
            ss += q.x * q.x + q.y * q.y + q.z * q.z + q.w * q.w;
        }
        for (int off = 32; off > 0; off >>= 1) ss += __shfl_down(ss, off);
        __shared__ float ls[4];
        int lane = tid & 63, w = tid >> 6;
        if (lane == 0) ls[w] = ss;
        __syncthreads();
        if (tid == 0)
            inv[b] = 1.0f / fmaxf(sqrtf(ls[0] + ls[1] + ls[2] + ls[3]), 1e-12f);
        return;
    }
    {   // zero partial + dots (float4)
        int idx = (bx - G2V_BLOCKS - SH_BLOCKS - S2P_BLOCKS - N_GRD) * 256 + tid;
        f4 z = {0.f, 0.f, 0.f, 0.f};
        if (idx < 204800)                 *(f4*)(partial + (size_t)idx * 4) = z;
        else if (idx - 204800 < 128)      *(f4*)(dots + (size_t)(idx - 204800) * 4) = z;
    }
}

// ---------------------------------------------------------------------------
// K2: MFMA correlation (round-3 structure + T5 setprio) + z-SLAB output.
// Grid (m=32, xs=5, z=8: h=z&1, qt=z>>1); 4 waves = i.
// A staged per cqi via global_load_lds(16) from sh (zero-redirect padding),
// guarded by __syncthreads (2x per kernel).
// B is WAVE-PRIVATE double-buffered, no barriers in the ii loop:
//    stage B(ii+1) -> s_waitcnt vmcnt(4) -> compute(ii)      [T3/T4]
// setprio(1) around the MFMA cluster [T5, +2.5% measured r10].
// OUTPUT: when zstride!=0, each z writes its own slab with plain f4 stores
// (no atomics -> no cross-XCD cacheline ping-pong; r10 counters showed
// 100MB WRITE_SIZE = ~32x amplification from 8-XCD atomic bouncing on a
// 3.2MB buffer).  zstride==0 falls back to the r10 atomicAdd path.
// LDS = 48384 A + 2*15360 B = 79104 -> 2 blocks/CU.
// ---------------------------------------------------------------------------
__global__ __launch_bounds__(256, 2) void corr_mfma_kernel(const _Float16* __restrict__ sh,
                                                           const _Float16* __restrict__ g2,
                                                           float* __restrict__ partial,
                                                           int zstride) {
    __shared__ __align__(16) char lds[79104];
    char* AB = lds;                 // 48384
    char* BB = lds + 48384;         // 2 x 15360: [bsel][w4][cp2][n4][g30]x16B

    const int m  = blockIdx.x;
    const int xs = blockIdx.y;
    const int z  = blockIdx.z;
    const int h  = z & 1;
    const int qt = z >> 1;

    const int x00 = (xs < 4) ? 16 * xs : 49;
    const int qb  = (xs < 4) ? 16 * xs : 48;
    const int xoff = x00 - qb;
    const int qstage = qb + 40 * h;

    const int tid  = threadIdx.x;
    const int w    = tid >> 6;
    const int lane = tid & 63;
    const int s    = lane & 15;
    const int u    = lane >> 4;
    const int cp   = (s + xoff) & 1;

    f4 acc[5][4];
#pragma unroll
    for (int t = 0; t < 5; ++t)
#pragma unroll
        for (int n = 0; n < 4; ++n) { acc[t][n][0]=0.f; acc[t][n][1]=0.f; acc[t][n][2]=0.f; acc[t][n][3]=0.f; }

    const int woff = (16 - xoff + cp + 2 * u - s) * 8;
    const char* Blane = BB + w * 3840 + cp * 1920 + woff;
    const int abase0 = s * 336 + u * 16;
    const int q2base = qstage >> 1;

    size_t bsrc[4];
    bool bs_on[4];
#pragma unroll
    for (int k = 0; k < 4; ++k) {
        int idx = k * 64 + lane;
        bs_on[k] = idx < 240;
        int cpp = idx / 120; int rm = idx - cpp * 120;
        int nn = rm / 30;    int gg = rm - nn * 30;
        bsrc[k] = (size_t)cpp * 868352 + (size_t)nn * 424
                + (size_t)(gg + 20 * h) * 8 + (size_t)w * 27136;
    }

    auto stageA = [&](int cq) {
        for (int k = 0; k < 11; ++k) {
            int idx = k * 256 + tid;
            if (idx < 2688) {
                u32 r = (u32)idx / 21u;
                u32 g = (u32)idx - r * 21u;
                int q2 = q2base + (int)g;
                bool valid = (g < 20u) & (r >= 32u) & (r < 96u) & (q2 >= 16) & (q2 < 48);
                const _Float16* src = valid
                    ? sh + ((((size_t)m * 8 + cq) * 64 + (r - 32)) * 32 + (q2 - 16)) * 8
                    : g2;   // first granules of g2 are structurally zero
                __builtin_amdgcn_global_load_lds(
                    (const __attribute__((address_space(1))) u32*)(const void*)src,
                    (__attribute__((address_space(3))) u32*)(void*)(AB + k * 4096 + w * 1024),
                    16, 0, 0);
            }
        }
    };

    auto stageB = [&](int cq, int ii, int bsel) {
        asm volatile("s_waitcnt lgkmcnt(0)" ::: "memory");
        char* dst0 = BB + bsel * 15360 + w * 3840;
        const size_t add = (size_t)cq * 108544 + (size_t)ii * 1696;
#pragma unroll
        for (int k = 0; k < 4; ++k) {
            if (bs_on[k])
                __builtin_amdgcn_global_load_lds(
                    (const __attribute__((address_space(1))) u32*)(const void*)(g2 + bsrc[k] + add),
                    (__attribute__((address_space(3))) u32*)(void*)(dst0 + k * 1024),
                    16, 0, 0);
        }
    };

    auto compute = [&](int ii, int bsel) {
        const char* Ab = AB + abase0 + (w * 16 + ii) * 336;
        const char* Bb = Blane + bsel * 15360;
#pragma unroll
        for (int qs = 0; qs < 5; ++qs) {
            h8 a[5]; h8 bfr[4];
#pragma unroll
            for (int n = 0; n < 4; ++n) bfr[n] = *(const h8*)(Bb + qs * 64 + n * 480);
#pragma unroll
            for (int t = 0; t < 5; ++t) a[t] = *(const h8*)(Ab + qs * 64 + t * 5376);
            __builtin_amdgcn_s_setprio(1);                 // T5: favor MFMA wave
#pragma unroll
            for (int t = 0; t < 5; ++t)
#pragma unroll
                for (int n = 0; n < 4; ++n)
                    acc[t][n] = __builtin_amdgcn_mfma_f32_16x16x32_f16(a[t], bfr[n], acc[t][n], 0, 0, 0);
            __builtin_amdgcn_s_setprio(0);
        }
    };

    for (int cqi = 0; cqi < 2; ++cqi) {
        const int cq = qt * 2 + cqi;
        __syncthreads();          // prior readers of AB/BB done
        stageA(cq);
        stageB(cq, 0, 0);
        __syncthreads();          // full drain: A + B(0) resident
#pragma unroll 1
        for (int iip = 0; iip < 8; ++iip) {
            const int ii0 = 2 * iip;
            stageB(cq, ii0 + 1, 1);
            asm volatile("s_waitcnt vmcnt(4)" ::: "memory");
            compute(ii0, 0);
            if (iip < 7) {
                stageB(cq, ii0 + 2, 0);
                asm volatile("s_waitcnt vmcnt(4)" ::: "memory");
            } else {
                asm volatile("s_waitcnt vmcnt(0)" ::: "memory");
            }
            compute(ii0 + 1, 1);
        }
    }

    // ---- cross-wave (i) reduce in LDS, then store/atomicAdd into output
    float* red = (float*)lds;
#pragma unroll
    for (int t = 0; t < 5; ++t) {
        __syncthreads();
#pragma unroll
        for (int nn = 0; nn < 4; ++nn)
            *(f4*)(red + ((nn * 4 + w) * 64 + lane) * 4) = acc[t][nn];
        __syncthreads();
        {
            int nn = tid >> 6, ln = tid & 63;
            f4 sum = *(f4*)(red + ((nn * 4 + 0) * 64 + ln) * 4);
            sum = sum + *(f4*)(red + ((nn * 4 + 1) * 64 + ln) * 4);
            sum = sum + *(f4*)(red + ((nn * 4 + 2) * 64 + ln) * 4);
            sum = sum + *(f4*)(red + ((nn * 4 + 3) * 64 + ln) * 4);
            int ss = ln & 15, uu = ln >> 4;
            float* dst = partial + (size_t)z * (size_t)zstride
                         + ((size_t)(m * 4 + nn)) * 6400
                         + (xs * 16 + ss) * 80 + t * 16 + uu * 4;
            if (zstride != 0) {
                *(f4*)dst = sum;                    // slab mode: plain store
            } else {
#pragma unroll
                for (int l = 0; l < 4; ++l) atomicAdd(dst + l, sum[l]);
            }
        }
    }
}

// ---------------------------------------------------------------------------
// K3: epilogue.  Builds the per-m prefix SAT in LDS from s2g (scan order
// bit-identical to the original), computes inv_sat locally; n==0 block
// persists S[m] + inv[4+m] for the refine kernels (later launches).
// Slab mode (zstride!=0): raw = sum over the 8 z-slabs.
// Then normalize + top-4 candidates per (m,n).
// ---------------------------------------------------------------------------
__global__ __launch_bounds__(256) void epilogue_kernel(const float* __restrict__ partial,
                                                       const float* __restrict__ s2g,
                                                       float* __restrict__ S,
                                                       float* __restrict__ inv,
                                                       const int* __restrict__ unc,
                                                       float* __restrict__ candv,
                                                       int* __restrict__ candi,
                                                       int zstride) {
    const int b = blockIdx.x;
    const int m = b >> 2, n = b & 3;
    const int tid = threadIdx.x;
    __shared__ float P[64][65];

    // build prefix SAT (exact replica of original scans)
    const float* sg = s2g + (size_t)m * 4096;
    for (int idx = tid; idx < 4096; idx += 256) P[idx >> 6][idx & 63] = sg[idx];
    __syncthreads();
    if (tid < 64) {
        int r = tid; float run = 0.0f;
        for (int w = 0; w < 64; ++w) { run += P[r][w]; P[r][w] = run; }
    }
    __syncthreads();
    if (tid < 64) {
        int c = tid; float run = 0.0f;
        for (int h = 0; h < 64; ++h) { run += P[h][c]; P[h][c] = run; }
    }
    __syncthreads();
    const float isn = 1.0f / fmaxf(sqrtf(P[63][63]), 1e-12f);
    if (n == 0) {
        if (tid == 0) inv[N_GRD + m] = isn;
        float* Sm = S + (size_t)m * (HO * WO);
        for (int p = tid; p < HO * WO; p += 256) {
            int r = p / 65, c = p - r * 65;
            Sm[p] = (r == 0 || c == 0) ? 0.0f : P[r - 1][c - 1];
        }
    }

    const float uu = (float)unc[0];
    const float sc = inv[n] * isn;
    const float* pb = partial + (size_t)(m * 4 + n) * 6400;

    float best = -3.4e38f;
    int bidx = 0x7fffffff;
    for (int pp = tid; pp < 4225; pp += 256) {
        int x = pp / 65, y = pp - x * 65;
        int xsl = (x == 64) ? 79 : x;
        int off = xsl * 80 + y;
        float raw = pb[off];
        if (zstride != 0) {
#pragma unroll
            for (int zz = 1; zz < 8; ++zz)
                raw += pb[(size_t)zz * (size_t)zstride + off];
        }
        float num = raw * sc;
        int r0 = max(0, y - 32), r1 = min(64, y + 32);
        int q0 = max(0, x - 32), q1 = min(64, x + 32);
        float s11 = P[r1 - 1][q1 - 1];
        float s01 = (r0 == 0) ? 0.0f : P[r0 - 1][q1 - 1];
        float s10 = (q0 == 0) ? 0.0f : P[r1 - 1][q0 - 1];
        float s00 = (r0 == 0 || q0 == 0) ? 0.0f : P[r0 - 1][q0 - 1];
        float ps = s11 - s01 - s10 + s00;
        float denom = fmaxf(sqrtf(ps) * isn * uu, 1e-12f);
        float v = num / denom;
        int p = y * 65 + x;
        if (v > best || (v == best && p < bidx)) { best = v; bidx = p; }
    }
    __shared__ float bv[256]; __shared__ int bi[256];
    __shared__ float cv[256]; __shared__ int ci[256];
    __shared__ int winner;
    bv[tid] = best; bi[tid] = bidx;
    __syncthreads();
    for (int round = 0; round < 4; ++round) {
        cv[tid] = bv[tid]; ci[tid] = bi[tid];
        __syncthreads();
        for (int st = 128; st > 0; st >>= 1) {
            if (tid < st) {
                float ov = cv[tid + st]; int oi = ci[tid + st];
                if (ov > cv[tid] || (ov == cv[tid] && oi < ci[tid])) { cv[tid] = ov; ci[tid] = oi; }
            }
            __syncthreads();
        }
        if (tid == 0) { candv[b * 4 + round] = cv[0]; candi[b * 4 + round] = ci[0]; winner = ci[0]; }
        __syncthreads();
        if (bi[tid] == winner) bv[tid] = -3.4e38f;
        __syncthreads();
    }
}

// ---------------------------------------------------------------------------
// K4a: exact fp32 dot for candidate (b,k), split over 8 c-chunks (grid z).
// atomicAdd partial dots (dots zeroed in prep).  No fences, early return.
// ---------------------------------------------------------------------------
__global__ __launch_bounds__(256) void refine_dot_kernel(const float* __restrict__ grd,
                                                         const float* __restrict__ sat,
                                                         const float* __restrict__ candv,
                                                         const int* __restrict__ candi,
                                                         float* __restrict__ dots) {
    const int b = blockIdx.x;
    const int k = blockIdx.y;
    const int cq = blockIdx.z;
    const int m = b >> 2, n = b & 3;
    float v0 = candv[b * 4];
    float thr = v0 - (0.02f * fabsf(v0) + 1e-4f);
    if (k > 0 && candv[b * 4 + k] < thr) return;   // dots stays 0 (zeroed)
    int p = candi[b * 4 + k];
    int y = p / 65, x = p - y * 65;
    const int tid = threadIdx.x, lane = tid & 63, w = tid >> 6;
    const int ilo = max(0, 32 - y), ihi = min(64, 96 - y);
    int xj = x + lane - 32;
    float acc = 0.0f;
    if (xj >= 0 && xj < 64) {
        const float* sm = sat + (size_t)m * SAMPLE_ELEMS;
        const float* gn = grd + (size_t)n * SAMPLE_ELEMS;
        for (int cc = 0; cc < 4; ++cc) {
            const int cbase = (cq * 4 + cc) << 12;
            const float* sp = sm + cbase + xj + ((y - 32) << 6);
            const float* gp = gn + cbase + lane;
            for (int i = ilo + w; i < ihi; i += 4)
                acc = fmaf(sp[i << 6], gp[i << 6], acc);
        }
    }
    for (int off = 32; off > 0; off >>= 1) acc += __shfl_down(acc, off);
    __shared__ float ls[4];
    if (lane == 0) ls[w] = acc;
    __syncthreads();
    if (tid == 0) atomicAdd(&dots[b * 4 + k], ls[0] + ls[1] + ls[2] + ls[3]);
}

// ---------------------------------------------------------------------------
// K4b: pick best refined candidate per (m,n), write outputs.  1 block.
// ---------------------------------------------------------------------------
__global__ __launch_bounds__(128) void refine_pick_kernel(const float* __restrict__ S,
                                                          const float* __restrict__ inv,
                                                          const int* __restrict__ unc,
                                                          const float* __restrict__ candv,
                                                          const int* __restrict__ candi,
                                                          const float* __restrict__ dots,
                                                          float* __restrict__ out) {
    int b = threadIdx.x;
    if (b >= 128) return;
    const int m = b >> 2, n = b & 3;
    const float uu = (float)unc[0];
    const float sc = inv[n] * inv[N_GRD + m];
    const float isn = inv[N_GRD + m];
    const float* Sm = S + (size_t)m * 4225;
    float v0 = candv[b * 4];
    float thr = v0 - (0.02f * fabsf(v0) + 1e-4f);
    float bestv = -3.4e38f; int bestp = 0x7fffffff;
    for (int k = 0; k < 4; ++k) {
        if (k > 0 && candv[b * 4 + k] < thr) break;   // candv sorted desc
        int p = candi[b * 4 + k];
        int y = p / 65, x = p - y * 65;
        int r0 = max(0, y - 32), r1 = min(64, y + 32);
        int q0 = max(0, x - 32), q1 = min(64, x + 32);
        float ps = Sm[r1 * 65 + q1] - Sm[r0 * 65 + q1] - Sm[r1 * 65 + q0] + Sm[r0 * 65 + q0];
        float denom = fmaxf(sqrtf(ps) * isn * uu, 1e-12f);
        float v = dots[b * 4 + k] * sc / denom;
        if (v > bestv || (v == bestv && p < bestp)) { bestv = v; bestp = p; }
    }
    out[b] = bestv;
    int row = bestp / 65, col = bestp - row * 65;
    float pr = -((float)row - 32.5f);
    float pc = (float)col - 32.5f;
    out[128 + b * 2 + 0] = ((pr * 0.2f) * 512.0f) * (1.0f / 128.0f);
    out[128 + b * 2 + 1] = ((pc * 0.2f) * 512.0f) * (1.0f / 128.0f);
}

// ---------------------------------------------------------------------------
extern "C" void kernel_launch(void* const* d_in, const int* in_sizes, int n_in,
                              void* d_out, int out_size, void* d_ws, size_t ws_size,
                              hipStream_t stream) {
    const float* grd = (const float*)d_in[0];
    const float* sat = (const float*)d_in[1];
    const int*   unc = (const int*)d_in[2];
    float* out = (float*)d_out;
    float* ws  = (float*)d_ws;

    float* inv     = ws + OFF_INV;
    float* S       = ws + OFF_S;
    float* candv   = ws + OFF_CANDV;
    int*   candi   = (int*)(ws + OFF_CANDI);
    float* dots    = ws + OFF_DOTS;
    float* partial = ws + OFF_PART;
    _Float16* g2   = (_Float16*)(ws + OFF_G2F);
    _Float16* sh   = (_Float16*)(ws + OFF_SH);
    float* s2g     = ws + OFF_S2G;

    // z-slab mode if the workspace is big enough (needs ~42.5 MB)
    const size_t need = ((size_t)OFF_SLAB + 8ull * ZSTRIDE) * sizeof(float);
    const int zstride = (ws_size >= need) ? ZSTRIDE : 0;
    float* corrout = zstride ? (ws + OFF_SLAB) : partial;

    prep_kernel<<<PREP_BLOCKS, 256, 0, stream>>>(grd, sat, g2, sh, s2g, inv, partial, dots);
    corr_mfma_kernel<<<dim3(M_SAT, 5, 8), 256, 0, stream>>>(sh, g2, corrout, zstride);
    epilogue_kernel<<<M_SAT * N_GRD, 256, 0, stream>>>(corrout, s2g, S, inv, unc, candv, candi, zstride);
    refine_dot_kernel<<<dim3(128, 4, 8), 256, 0, stream>>>(grd, sat, candv, candi, dots);
    refine_pick_kernel<<<1, 128, 0, stream>>>(S, inv, unc, candv, candi, dots, out);
}